// Round 11
// baseline (617.933 us; speedup 1.0000x reference)
//
#include <hip/hip_runtime.h>
#include <float.h>
#include <math.h>

#define NB 2
#define MQ 16384
#define NQ (NB*MQ)          // 32768 queries
#define PP 5023
#define KNN 4
#define HPX 256
#define HWSZ (HPX*HPX)      // 65536
#define GD 12               // grid dim
#define GC (GD*GD*GD)       // 1728 cells
#define CAND_MAX 1024

// output layout (floats): densities[NQ], rgb[NQ*32], dist[NQ*4]
#define OUT_RGB_OFF  ((size_t)NQ)
#define OUT_DIST_OFF ((size_t)NQ + (size_t)NQ*32)

// workspace layout (bytes)
#define WS_SUMS_OFF   ((size_t)0x80000)
#define WS_PCNT_OFF   ((size_t)0x81000)
#define WS_PSTART_OFF ((size_t)0x85000)
#define WS_PCUR_OFF   ((size_t)0x89000)
#define WS_QCNT_OFF   ((size_t)0x8D000)
#define WS_QSTART_OFF ((size_t)0x91000)
#define WS_QCUR_OFF   ((size_t)0x95000)
#define WS_QID_OFF    ((size_t)0x99000)      // 32768*4 = 128 KB
#define WS_PG_OFF     ((size_t)0xC0000)      // 2*5023*16
#define WS_PID_OFF    ((size_t)0xF0000)      // 2*5023*4
#define WS_WP_OFF     ((size_t)0x100000)     // 29504 u32
#define WS_TEX_OFF    ((size_t)0x120000)     // 48 MB transposed tex

// packed-weight sub-offsets (u32 units)
#define WP_PW1 0
#define WP_PW2 1920
#define WP_FW1 2944
#define WP_FW2 7040
#define WP_FW3 15232
#define WP_DW  23424
#define WP_RW1 23488
#define WP_RW2 28480

typedef __attribute__((ext_vector_type(2))) _Float16 half2v;

static __device__ __forceinline__ unsigned int pk2(float a, float b) {
    half2v h; h[0] = (_Float16)a; h[1] = (_Float16)b;   // RNE converts
    return __builtin_bit_cast(unsigned int, h);
}
static __device__ __forceinline__ float2 upk(unsigned int u) {
    half2v h = __builtin_bit_cast(half2v, u);
    return make_float2((float)h[0], (float)h[1]);
}
static __device__ __forceinline__ float dot2(unsigned int a, unsigned int b, float c) {
    return __builtin_amdgcn_fdot2(__builtin_bit_cast(half2v, a),
                                  __builtin_bit_cast(half2v, b), c, false);
}
static __device__ __forceinline__ int cell_of(float x) {
    int g = (int)(x * (float)GD);
    return (g < 0) ? 0 : ((g > GD-1) ? GD-1 : g);
}

// ------------------------------------------------------------------
struct PackArgs {
    const float* src[8];
    int off[8]; int din[8]; int dout[8];
};
__global__ __launch_bounds__(256) void k_pack(PackArgs a, unsigned int* wp) {
    const int mid = blockIdx.y;
    const int idx = blockIdx.x * 256 + threadIdx.x;
    const int DIN = a.din[mid], DOUT = a.dout[mid];
    const int din2 = (DIN + 1) >> 1;
    if (idx >= din2 * DOUT) return;
    const int i2 = idx / DOUT, j = idx - i2 * DOUT;
    const float* s = a.src[mid];
    const float lo = s[(2*i2) * DOUT + j];
    const float hi = (2*i2 + 1 < DIN) ? s[(2*i2 + 1) * DOUT + j] : 0.f;
    wp[a.off[mid] + idx] = pk2(lo, hi);
}

// ------------------------------------------------------------------
__global__ __launch_bounds__(256) void k_transpose(const float* __restrict__ src,
                                                   float* __restrict__ dst) {
    const int tid = threadIdx.x;
    const int b = blockIdx.x;            // 6*256 blocks
    const int n3 = b >> 8;
    const int hw = ((b & 255) << 8) + tid;
    const float* s = src + (size_t)n3 * 32 * HWSZ + hw;
    float v[32];
#pragma unroll
    for (int c = 0; c < 32; ++c) v[c] = s[(size_t)c * HWSZ];
    float4* d = (float4*)(dst + ((size_t)n3 * HWSZ + hw) * 32);
#pragma unroll
    for (int c = 0; c < 8; ++c) d[c] = make_float4(v[4*c], v[4*c+1], v[4*c+2], v[4*c+3]);
}

// ------------------------------------------------------------------
// bucket builds
__global__ __launch_bounds__(256) void k_gcount(const float* __restrict__ pts,
                                                unsigned int* __restrict__ cnt) {
    const int i = blockIdx.x * 256 + threadIdx.x;
    if (i >= NB * PP) return;
    const int n = (i >= PP) ? 1 : 0;
    const float px = pts[3*i], py = pts[3*i+1], pz = pts[3*i+2];
    const int c = (cell_of(pz)*GD + cell_of(py))*GD + cell_of(px);
    atomicAdd(&cnt[n*GC + c], 1u);
}
__global__ __launch_bounds__(256) void k_qcount(const float* __restrict__ coords,
                                                unsigned int* __restrict__ cnt) {
    const int q = blockIdx.x * 256 + threadIdx.x;
    if (q >= NQ) return;
    const int n = q >> 14;
    const float cx = coords[3*q], cy = coords[3*q+1], cz = coords[3*q+2];
    const int c = (cell_of(cz)*GD + cell_of(cy))*GD + cell_of(cx);
    atomicAdd(&cnt[n*GC + c], 1u);
}

__global__ __launch_bounds__(1024) void k_scan(const unsigned int* __restrict__ cnt,
                                               unsigned int* __restrict__ start,
                                               unsigned int* __restrict__ cursor,
                                               int stride) {
    __shared__ unsigned int sc[1024];
    const int t = threadIdx.x;
#pragma unroll 1
    for (int n = 0; n < 2; ++n) {
        const unsigned int* c = cnt + n*GC;
        unsigned int a = (2*t   < GC) ? c[2*t]   : 0u;
        unsigned int b = (2*t+1 < GC) ? c[2*t+1] : 0u;
        unsigned int s = a + b;
        sc[t] = s;
        __syncthreads();
        for (int off = 1; off < 1024; off <<= 1) {
            unsigned int v = (t >= off) ? sc[t - off] : 0u;
            __syncthreads();
            sc[t] += v;
            __syncthreads();
        }
        unsigned int excl = sc[t] - s;
        unsigned int base = n * stride;
        if (2*t < GC)   { start[n*GC + 2*t]   = base + excl;
                          cursor[n*GC + 2*t]  = base + excl; }
        if (2*t+1 < GC) { start[n*GC + 2*t+1] = base + excl + a;
                          cursor[n*GC + 2*t+1]= base + excl + a; }
        __syncthreads();
    }
}

__global__ __launch_bounds__(256) void k_gscatter(const float* __restrict__ pts,
                                                  unsigned int* __restrict__ cursor,
                                                  float4* __restrict__ pg,
                                                  int* __restrict__ pid) {
    const int i = blockIdx.x * 256 + threadIdx.x;
    if (i >= NB * PP) return;
    const int n = (i >= PP) ? 1 : 0;
    const int local = i - n * PP;
    const float px = pts[3*i], py = pts[3*i+1], pz = pts[3*i+2];
    const int c = (cell_of(pz)*GD + cell_of(py))*GD + cell_of(px);
    const unsigned int pos = atomicAdd(&cursor[n*GC + c], 1u);
    pg[pos] = make_float4(px, py, pz, fmaf(px, px, fmaf(py, py, pz*pz)));
    pid[pos] = local;
}
__global__ __launch_bounds__(256) void k_qscatter(const float* __restrict__ coords,
                                                  unsigned int* __restrict__ cursor,
                                                  int* __restrict__ qid) {
    const int q = blockIdx.x * 256 + threadIdx.x;
    if (q >= NQ) return;
    const int n = q >> 14;
    const float cx = coords[3*q], cy = coords[3*q+1], cz = coords[3*q+2];
    const int c = (cell_of(cz)*GD + cell_of(cy))*GD + cell_of(cx);
    const unsigned int pos = atomicAdd(&cursor[n*GC + c], 1u);
    qid[pos] = q;
}

// ------------------------------------------------------------------
// KNN (R10, proven): one block per (n,cell); ring<=2 candidates in LDS;
// 16-lane group per query; exact (d2,idx) top-4 + butterfly merge.
__global__ __launch_bounds__(256) void k_knn_cell(
    const float* __restrict__ coords,
    const unsigned int* __restrict__ pstart, const unsigned int* __restrict__ pcnt,
    const float4* __restrict__ pg, const int* __restrict__ pid,
    const unsigned int* __restrict__ qstart, const unsigned int* __restrict__ qcnt,
    const int* __restrict__ qid,
    float* __restrict__ odist, int* __restrict__ oidx)
{
    __shared__ float4 cand[CAND_MAX];        // 16 KB
    __shared__ int    cidx[CAND_MAX];        // 4 KB
    __shared__ unsigned int cs[125], cc[125], co[126];
    const int tid = threadIdx.x;
    const int bid = blockIdx.x;              // 2*GC
    const int n = bid / GC, c = bid % GC;
    const unsigned int qn = qcnt[n*GC + c];
    if (qn == 0) return;
    const int gz = c / (GD*GD), gy = (c / GD) % GD, gx = c % GD;

    const int x0 = max(gx-2,0), x1 = min(gx+2,GD-1), nx = x1-x0+1;
    const int y0 = max(gy-2,0), y1 = min(gy+2,GD-1), ny = y1-y0+1;
    const int z0 = max(gz-2,0), z1 = min(gz+2,GD-1), nz = z1-z0+1;
    const int ncell = nx*ny*nz;

    if (tid < ncell) {
        const int xx = x0 + tid % nx;
        const int yy = y0 + (tid / nx) % ny;
        const int zz = z0 + tid / (nx*ny);
        const int cid = n*GC + (zz*GD + yy)*GD + xx;
        cs[tid] = pstart[cid];
        cc[tid] = pcnt[cid];
    }
    __syncthreads();
    if (tid == 0) {
        unsigned int acc = 0;
        co[0] = 0;
        for (int t = 0; t < ncell; ++t) { acc += cc[t]; co[t+1] = acc; }
    }
    __syncthreads();
    const unsigned int total = co[ncell];
    const bool ovf = (total > CAND_MAX);
    if (!ovf) {
#pragma unroll 1
        for (int t = 0; t < ncell; ++t) {
            const unsigned int m = cc[t];
            if (tid < (int)m) {
                cand[co[t] + tid] = pg[cs[t] + tid];
                cidx[co[t] + tid] = pid[cs[t] + tid];
            }
        }
    }
    __syncthreads();

    const float w = 1.0f / (float)GD;
    const float thresh = 4.f * w * w * 0.999f;
    const int grp = tid >> 4, l16 = tid & 15;
    const unsigned int qs = qstart[n*GC + c];

#define INS4(d, i) { \
        bool L3 = ((d) < bd3) || ((d) == bd3 && (i) < bi3); \
        bool L2 = ((d) < bd2) || ((d) == bd2 && (i) < bi2); \
        bool L1 = ((d) < bd1) || ((d) == bd1 && (i) < bi1); \
        bool L0 = ((d) < bd0) || ((d) == bd0 && (i) < bi0); \
        bd3 = L3 ? (L2 ? bd2 : (d)) : bd3;  bi3 = L3 ? (L2 ? bi2 : (i)) : bi3; \
        bd2 = L2 ? (L1 ? bd1 : (d)) : bd2;  bi2 = L2 ? (L1 ? bi1 : (i)) : bi2; \
        bd1 = L1 ? (L0 ? bd0 : (d)) : bd1;  bi1 = L1 ? (L0 ? bi0 : (i)) : bi1; \
        bd0 = L0 ? (d) : bd0;               bi0 = L0 ? (i) : bi0; }

#define MERGE16() { \
        float bd[4] = { bd0, bd1, bd2, bd3 }; \
        int   bi[4] = { bi0, bi1, bi2, bi3 }; \
        for (int mask = 1; mask < 16; mask <<= 1) { \
            float od[4]; int oi[4]; \
            for (int j = 0; j < 4; ++j) { od[j] = __shfl_xor(bd[j], mask); \
                                          oi[j] = __shfl_xor(bi[j], mask); } \
            float e[4]; int ei[4]; \
            for (int j = 0; j < 4; ++j) { \
                float ad = bd[j], xd = od[3-j]; \
                int   ai = bi[j], xi = oi[3-j]; \
                bool ta = (ad < xd) || (ad == xd && ai < xi); \
                e[j] = ta ? ad : xd; ei[j] = ta ? ai : xi; \
            } \
            { bool sw = (e[2] < e[0]) || (e[2] == e[0] && ei[2] < ei[0]); \
              if (sw) { float td=e[0]; e[0]=e[2]; e[2]=td; int ti=ei[0]; ei[0]=ei[2]; ei[2]=ti; } } \
            { bool sw = (e[3] < e[1]) || (e[3] == e[1] && ei[3] < ei[1]); \
              if (sw) { float td=e[1]; e[1]=e[3]; e[3]=td; int ti=ei[1]; ei[1]=ei[3]; ei[3]=ti; } } \
            { bool sw = (e[1] < e[0]) || (e[1] == e[0] && ei[1] < ei[0]); \
              if (sw) { float td=e[0]; e[0]=e[1]; e[1]=td; int ti=ei[0]; ei[0]=ei[1]; ei[1]=ti; } } \
            { bool sw = (e[3] < e[2]) || (e[3] == e[2] && ei[3] < ei[2]); \
              if (sw) { float td=e[2]; e[2]=e[3]; e[3]=td; int ti=ei[2]; ei[2]=ei[3]; ei[3]=ti; } } \
            for (int j = 0; j < 4; ++j) { bd[j] = e[j]; bi[j] = ei[j]; } \
        } \
        bd0 = bd[0]; bd1 = bd[1]; bd2 = bd[2]; bd3 = bd[3]; \
        bi0 = bi[0]; bi1 = bi[1]; bi2 = bi[2]; bi3 = bi[3]; }

#pragma unroll 1
    for (unsigned int qb = 0; qb < qn; qb += 16) {
        const unsigned int qi = qb + grp;
        if (qi >= qn) continue;
        const int q = qid[qs + qi];
        const float cx = coords[3*q], cy = coords[3*q+1], cz = coords[3*q+2];
        const float ccq = fmaf(cx, cx, fmaf(cy, cy, cz*cz));

        float bd0 = FLT_MAX, bd1 = FLT_MAX, bd2 = FLT_MAX, bd3 = FLT_MAX;
        int   bi0 = 0x7fffffff, bi1 = 0x7fffffff, bi2 = 0x7fffffff, bi3 = 0x7fffffff;

        if (!ovf) {
#pragma unroll 1
            for (unsigned int j = l16; j < total; j += 16) {
                const float4 P = cand[j];
                const int i = cidx[j];
                const float dt = fmaf(cx, P.x, fmaf(cy, P.y, cz * P.z));
                const float d = fmaf(-2.0f, dt, ccq + P.w);
                INS4(d, i)
            }
            MERGE16()
        }
        if (ovf || !(bd3 < thresh)) {
            bd0 = bd1 = bd2 = bd3 = FLT_MAX;
            bi0 = bi1 = bi2 = bi3 = 0x7fffffff;
#pragma unroll 1
            for (int j = l16; j < PP; j += 16) {
                const float4 P = pg[n*PP + j];
                const int i = pid[n*PP + j];
                const float dt = fmaf(cx, P.x, fmaf(cy, P.y, cz * P.z));
                const float d = fmaf(-2.0f, dt, ccq + P.w);
                INS4(d, i)
            }
            MERGE16()
        }
        if (l16 == 0) {
            *(float4*)(odist + (size_t)q*4) = make_float4(bd0, bd1, bd2, bd3);
            *(int4*)(oidx + (size_t)q*4)    = make_int4(bi0, bi1, bi2, bi3);
        }
    }
#undef INS4
#undef MERGE16
}

// ------------------------------------------------------------------
__global__ __launch_bounds__(1024) void k_sums(const float* __restrict__ dist,
                                               float* __restrict__ sums) {
    const int b = blockIdx.x;            // n*4+k, 8 blocks
    const int n = b >> 2, k = b & 3;
    float s = 0.f;
    for (int m = threadIdx.x; m < MQ; m += 1024)
        s += 1.0f / dist[((size_t)n * MQ + m) * 4 + k];
    __shared__ float red[1024];
    red[threadIdx.x] = s;
    __syncthreads();
    for (int off = 512; off > 0; off >>= 1) {
        if (threadIdx.x < off) red[threadIdx.x] += red[threadIdx.x + off];
        __syncthreads();
    }
    if (threadIdx.x == 0) sums[b] = red[0];
}

// ------------------------------------------------------------------
// gemv over LDS: activations per-lane (conflict-free), weights from LDS
// window at wave-uniform address (broadcast ds_read_b128).
template<int DIN2, int DOUT, int TILE>
__device__ __forceinline__ void gemv_w(const unsigned int* Xp, int lane,
                                       const unsigned int* Wl,
                                       const float* __restrict__ bias,
                                       int j0, float (&acc)[TILE]) {
    static_assert(TILE % 4 == 0, "");
#pragma unroll
    for (int u = 0; u < TILE; ++u) acc[u] = bias[j0 + u];
#pragma unroll
    for (int i2 = 0; i2 < DIN2; ++i2) {
        const unsigned int xv = Xp[i2 * 64 + lane];
        const uint4* wr = (const uint4*)(Wl + i2 * DOUT + j0);
#pragma unroll
        for (int t = 0; t < TILE/4; ++t) {
            const uint4 w4 = wr[t];
            acc[4*t+0] = dot2(xv, w4.x, acc[4*t+0]);
            acc[4*t+1] = dot2(xv, w4.y, acc[4*t+1]);
            acc[4*t+2] = dot2(xv, w4.z, acc[4*t+2]);
            acc[4*t+3] = dot2(xv, w4.w, acc[4*t+3]);
        }
    }
}
template<int DIN2, int DOUT, int TILE>
__device__ __forceinline__ void gemv_aw(const unsigned int* Xp, int lane,
                                        const unsigned int* Wl,
                                        int j0, float (&acc)[TILE]) {
    static_assert(TILE % 4 == 0, "");
#pragma unroll
    for (int i2 = 0; i2 < DIN2; ++i2) {
        const unsigned int xv = Xp[i2 * 64 + lane];
        const uint4* wr = (const uint4*)(Wl + i2 * DOUT + j0);
#pragma unroll
        for (int t = 0; t < TILE/4; ++t) {
            const uint4 w4 = wr[t];
            acc[4*t+0] = dot2(xv, w4.x, acc[4*t+0]);
            acc[4*t+1] = dot2(xv, w4.y, acc[4*t+1]);
            acc[4*t+2] = dot2(xv, w4.z, acc[4*t+2]);
            acc[4*t+3] = dot2(xv, w4.w, acc[4*t+3]);
        }
    }
}

static __device__ __forceinline__ float harm_val(int h, float rx, float ry, float rz) {
    if (h >= 27) return 0.f;
    float v;
    if (h < 24) {
        int base = (h < 12) ? h : (h - 12);
        float rv = (base >> 2) == 0 ? rx : ((base >> 2) == 1 ? ry : rz);
        float e = rv * (float)(1 << (base & 3));
        v = (h < 12) ? sinf(e) : cosf(e);
    } else {
        v = (h == 24) ? rx : ((h == 25) ? ry : rz);
    }
    return v;
}

// ------------------------------------------------------------------
// main v11: scalar wv; weights staged into 8 KB LDS windows (synchronous,
// no prefetch registers -> no spill); broadcast ds_read weights.
// S 40 KB + WA/WB 16 KB = 56 KB -> 2 blocks/CU (32 waves) at VGPR<=64.
//
// S rows (u32 x 64): 0..63 p2out -> dense1 -> rw1out(0..31);
// 64..95 feat (tex 64..79, pts 80..95) -> ray-harm rows 64..77;
// 96..125 x59 (per pass) / 96..159 dense0; 128..159 h1 (per pass).
__global__ __launch_bounds__(1024, 2) void k_main(
    const float* __restrict__ coords, const float* __restrict__ dirs,
    const float* __restrict__ pts, const float* __restrict__ tex_raw,
    const float* __restrict__ tex_t, const float* __restrict__ emb,
    const unsigned int* __restrict__ wp,
    const float* __restrict__ pb1, const float* __restrict__ pb2,
    const float* __restrict__ fb1, const float* __restrict__ fb2,
    const float* __restrict__ fb3, const float* __restrict__ db,
    const float* __restrict__ rb1, const float* __restrict__ rb2,
    const int* __restrict__ idxbuf, const float* __restrict__ distbuf,
    const float* __restrict__ sums, float* __restrict__ out, int use_tex_t)
{
    __shared__ unsigned int S[160 * 64];             // 40 KB
    __shared__ __align__(16) unsigned int WA[2048];  // 8 KB
    __shared__ __align__(16) unsigned int WB[2048];  // 8 KB
    const int tid  = threadIdx.x;
    const int lane = tid & 63;
    const int wv   = __builtin_amdgcn_readfirstlane(tid >> 6);   // scalar 0..15
    const int q0   = blockIdx.x * 64;
    const int n    = q0 >> 14;
    const int q    = q0 + lane;

#define STAGE(dst, off, len) { for (int i_ = tid; i_ < (len); i_ += 1024) (dst)[i_] = wp[(off) + i_]; }

    // ---------- tex sampling -> fp32 regs (2 ch/wave) ----------
    float tex_acc[2] = {0.f, 0.f};
    {
        const int g = wv;
        const float cx = coords[q*3+0], cy = coords[q*3+1], cz = coords[q*3+2];
#pragma unroll
        for (int pl = 0; pl < 3; ++pl) {
            float gx = (pl == 2) ? cz : cx;
            float gy = (pl == 0) ? cy : ((pl == 1) ? cz : cx);
            float x = (gx + 1.f) * 128.f - 0.5f;
            float y = (gy + 1.f) * 128.f - 0.5f;
            float x0f = floorf(x), y0f = floorf(y);
            float wx1 = x - x0f, wy1 = y - y0f;
            float wx0 = 1.f - wx1, wy0 = 1.f - wy1;
            int x0 = (int)x0f, y0 = (int)y0f;
            int n3 = n * 3 + pl;
            int  xs[4] = { x0, x0+1, x0,   x0+1 };
            int  ys[4] = { y0, y0,   y0+1, y0+1 };
            float wt[4] = { wx0*wy0, wx1*wy0, wx0*wy1, wx1*wy1 };
#pragma unroll
            for (int c = 0; c < 4; ++c) {
                int xi = xs[c], yi = ys[c];
                if (xi >= 0 && xi < HPX && yi >= 0 && yi < HPX) {
                    float wgt = wt[c];
                    if (use_tex_t) {
                        const float2 a = *(const float2*)(tex_t +
                            (((size_t)n3 * HWSZ + (size_t)yi * HPX + xi) * 32 + g * 2));
                        tex_acc[0] = fmaf(wgt, a.x, tex_acc[0]);
                        tex_acc[1] = fmaf(wgt, a.y, tex_acc[1]);
                    } else {
                        size_t base = ((size_t)(n3 * 32 + g * 2)) * HWSZ + (size_t)yi * HPX + xi;
                        tex_acc[0] = fmaf(wgt, tex_raw[base], tex_acc[0]);
                        tex_acc[1] = fmaf(wgt, tex_raw[base + HWSZ], tex_acc[1]);
                    }
                }
            }
        }
        tex_acc[0] *= (1.f / 3.f); tex_acc[1] *= (1.f / 3.f);
    }

    STAGE(WA, WP_PW1, 1920)          // pw1, resident for all 4 passes
    STAGE(WB, WP_PW2, 1024)          // pw2, resident for all 4 passes

    // ---------- neighbor loop: 4 single-neighbor passes ----------
#pragma unroll 1
    for (int k = 0; k < KNN; ++k) {
        // A_k: build x59 rows 96..125 (emb 96..111, harm 112..125)
        {
            const int id = idxbuf[(size_t)q*4 + k];
            if (wv < 8) {
                const float4 e = *(const float4*)(emb + (size_t)id * 32 + wv*4);
                S[(96 + 2*wv    )*64 + lane] = pk2(e.x, e.y);
                S[(96 + 2*wv + 1)*64 + lane] = pk2(e.z, e.w);
            } else {
                const int w8 = wv - 8;
                const float cx = coords[q*3+0], cy = coords[q*3+1], cz = coords[q*3+2];
                const float nx = pts[((size_t)n*PP + id)*3 + 0];
                const float ny = pts[((size_t)n*PP + id)*3 + 1];
                const float nz = pts[((size_t)n*PP + id)*3 + 2];
                float rx = cx - nx, ry = cy - ny, rz = cz - nz;
                float nrm = sqrtf(fmaf(rx, rx, fmaf(ry, ry, rz*rz)));
                float inv = 1.f / fmaxf(nrm, 1e-12f);
                rx *= inv; ry *= inv; rz *= inv;
                if (w8 < 7) {
#pragma unroll
                    for (int t = 0; t < 2; ++t) {
                        const int pr = 2*w8 + t;          // 0..13
                        S[(112 + pr)*64 + lane] =
                            pk2(harm_val(2*pr, rx, ry, rz), harm_val(2*pr + 1, rx, ry, rz));
                    }
                }
            }
        }
        __syncthreads();
        // B_k: p1 59->64 relu (WA) -> h1 rows 128..159
        {
            float acc[4];
            gemv_w<30, 64, 4>(S + 96*64, lane, WA, pb1, wv * 4, acc);
            S[(128 + 2*wv    )*64 + lane] = pk2(fmaxf(acc[0], 0.f), fmaxf(acc[1], 0.f));
            S[(128 + 2*wv + 1)*64 + lane] = pk2(fmaxf(acc[2], 0.f), fmaxf(acc[3], 0.f));
        }
        __syncthreads();
        // C_k: p2 64->32 (WB), wk-scaled -> row k*16 + wv
        {
            float acc[2];
            acc[0] = pb2[wv*2 + 0]; acc[1] = pb2[wv*2 + 1];
#pragma unroll
            for (int i2 = 0; i2 < 32; ++i2) {
                const unsigned int xv = S[(128 + i2)*64 + lane];
                acc[0] = dot2(xv, WB[i2*32 + wv*2 + 0], acc[0]);
                acc[1] = dot2(xv, WB[i2*32 + wv*2 + 1], acc[1]);
            }
            const float dist = distbuf[(size_t)q*4 + k];
            const float wk = (1.0f / dist) / sums[n*4 + k];
            S[(k*16 + wv)*64 + lane] = pk2(wk * acc[0], wk * acc[1]);
        }
        __syncthreads();
    }

    // ---------- D: feat rows 64..95; stage fw1 halves ----------
    {
        S[(64 + wv)*64 + lane] = pk2(tex_acc[0], tex_acc[1]);
        float a = 0.f, b = 0.f;
#pragma unroll
        for (int k = 0; k < 4; ++k) {
            float2 v = upk(S[(k*16 + wv)*64 + lane]);
            a += v.x; b += v.y;
        }
        S[(80 + wv)*64 + lane] = pk2(a, b);
    }
    STAGE(WA, WP_FW1, 2048)
    STAGE(WB, WP_FW1 + 2048, 2048)
    __syncthreads();
    // ---------- E: fw1 64->128 relu -> dense0 rows 96..159 ----------
    {
        float acc[8];
#pragma unroll
        for (int u = 0; u < 8; ++u) acc[u] = fb1[wv*8 + u];
        gemv_aw<16, 128, 8>(S + 64*64, lane, WA, wv*8, acc);
        gemv_aw<16, 128, 8>(S + 80*64, lane, WB, wv*8, acc);
#pragma unroll
        for (int u = 0; u < 4; ++u)
            S[(96 + 4*wv + u)*64 + lane] = pk2(fmaxf(acc[2*u], 0.f), fmaxf(acc[2*u+1], 0.f));
    }
    __syncthreads();
    STAGE(WA, WP_FW2, 2048)
    STAGE(WB, WP_FW2 + 2048, 2048)
    __syncthreads();
    // ---------- F: fw2 128->128 relu -> dense1 rows 0..63 ----------
    float accF[8];
#pragma unroll
    for (int u = 0; u < 8; ++u) accF[u] = fb2[wv*8 + u];
    gemv_aw<16, 128, 8>(S +  96*64, lane, WA, wv*8, accF);
    gemv_aw<16, 128, 8>(S + 112*64, lane, WB, wv*8, accF);
    __syncthreads();
    STAGE(WA, WP_FW2 + 4096, 2048)
    STAGE(WB, WP_FW2 + 6144, 2048)
    __syncthreads();
    gemv_aw<16, 128, 8>(S + 128*64, lane, WA, wv*8, accF);
    gemv_aw<16, 128, 8>(S + 144*64, lane, WB, wv*8, accF);
#pragma unroll
    for (int u = 0; u < 4; ++u)
        S[(4*wv + u)*64 + lane] = pk2(fmaxf(accF[2*u], 0.f), fmaxf(accF[2*u+1], 0.f));
    __syncthreads();
    STAGE(WA, WP_FW3, 2048)
    STAGE(WB, WP_FW3 + 2048, 2048)
    __syncthreads();
    // ---------- G: fw3 128->128 -> dense0 rows 96..159 (+ ray harm) ----------
    float accG[8];
#pragma unroll
    for (int u = 0; u < 8; ++u) accG[u] = fb3[wv*8 + u];
    gemv_aw<16, 128, 8>(S +  0*64, lane, WA, wv*8, accG);
    gemv_aw<16, 128, 8>(S + 16*64, lane, WB, wv*8, accG);
    __syncthreads();
    STAGE(WA, WP_FW3 + 4096, 2048)
    STAGE(WB, WP_FW3 + 6144, 2048)
    __syncthreads();
    gemv_aw<16, 128, 8>(S + 32*64, lane, WA, wv*8, accG);
    gemv_aw<16, 128, 8>(S + 48*64, lane, WB, wv*8, accG);
#pragma unroll
    for (int u = 0; u < 4; ++u)
        S[(96 + 4*wv + u)*64 + lane] = pk2(accG[2*u], accG[2*u+1]);
    if (wv < 14) {                       // ray harmonics -> rows 64..77
        float dx = dirs[q*3+0], dy = dirs[q*3+1], dz = dirs[q*3+2];
        float dn = sqrtf(fmaf(dx, dx, fmaf(dy, dy, dz*dz)));
        float inv = 1.f / fmaxf(dn, 1e-12f);
        dx *= inv; dy *= inv; dz *= inv;
        S[(64 + wv)*64 + lane] = pk2(harm_val(2*wv, dx, dy, dz),
                                     harm_val(2*wv + 1, dx, dy, dz));
    }
    __syncthreads();
    STAGE(WA, WP_RW1, 1664)
    STAGE(WB, WP_RW1 + 1664, 1664)
    __syncthreads();
    // ---------- I: rw1 155->64 relu -> rows 0..31 ----------
    const int j0r = wv * 4;
    float accI[4];
#pragma unroll
    for (int u = 0; u < 4; ++u) accI[u] = rb1[j0r + u];
    gemv_aw<26, 64, 4>(S +  96*64, lane, WA, j0r, accI);   // i2 0..25
    gemv_aw<26, 64, 4>(S + 122*64, lane, WB, j0r, accI);   // i2 26..51
    __syncthreads();
    STAGE(WA, WP_RW1 + 3328, 1664)
    STAGE(WB, WP_RW2, 1024)
    { for (int i_ = tid; i_ < 64; i_ += 1024) WB[1024 + i_] = wp[WP_DW + i_]; }
    __syncthreads();
    {
#pragma unroll
        for (int t = 0; t < 26; ++t) {                      // i2 52..77
            const int i2 = 52 + t;
            const int row = (i2 < 64) ? (96 + i2) : i2;     // harm rows 64..77
            const unsigned int xv = S[row*64 + lane];
            const uint4 w4 = *(const uint4*)(WA + t*64 + j0r);
            accI[0] = dot2(xv, w4.x, accI[0]);
            accI[1] = dot2(xv, w4.y, accI[1]);
            accI[2] = dot2(xv, w4.z, accI[2]);
            accI[3] = dot2(xv, w4.w, accI[3]);
        }
        S[(2*wv    )*64 + lane] = pk2(fmaxf(accI[0], 0.f), fmaxf(accI[1], 0.f));
        S[(2*wv + 1)*64 + lane] = pk2(fmaxf(accI[2], 0.f), fmaxf(accI[3], 0.f));
    }
    __syncthreads();
    // ---------- J: rw2 64->32 + sigmoid; density (wave 15) ----------
    {
        float acc[2];
        acc[0] = rb2[wv*2 + 0]; acc[1] = rb2[wv*2 + 1];
#pragma unroll
        for (int i2 = 0; i2 < 32; ++i2) {
            const unsigned int xv = S[i2*64 + lane];
            acc[0] = dot2(xv, WB[i2*32 + wv*2 + 0], acc[0]);
            acc[1] = dot2(xv, WB[i2*32 + wv*2 + 1], acc[1]);
        }
#pragma unroll
        for (int u = 0; u < 2; ++u) {
            int j = wv*2 + u;
            float v = acc[u];
            if (j < 3) v = 1.002f * (1.f / (1.f + expf(-v))) - 0.001f;
            out[OUT_RGB_OFF + (size_t)q*32 + j] = v;
        }
        if (wv == 15) {
            float z = db[0];
#pragma unroll 1
            for (int i2 = 0; i2 < 64; ++i2)
                z = dot2(S[(96 + i2)*64 + lane], WB[1024 + i2], z);
            const float cx = coords[q*3+0], cy = coords[q*3+1], cz = coords[q*3+2];
            float selv = (cx > -1.f && cx < 1.f && cy > -1.f && cy < 1.f &&
                          cz > -1.f && cz < 1.f) ? 1.f : 0.f;
            float t10 = 10.f * z;
            float sp = (t10 > 20.f) ? t10 : log1pf(expf(t10));
            float raw = sp * 0.1f * selv;
            out[q] = 1.f - expf(-raw);
        }
    }
#undef STAGE
}

// ------------------------------------------------------------------
extern "C" void kernel_launch(void* const* d_in, const int* in_sizes, int n_in,
                              void* d_out, int out_size, void* d_ws, size_t ws_size,
                              hipStream_t stream) {
    (void)in_sizes; (void)n_in; (void)out_size;
    const float* coords = (const float*)d_in[0];
    const float* dirs   = (const float*)d_in[1];
    const float* pts    = (const float*)d_in[2];
    const float* tex    = (const float*)d_in[3];
    const float* emb    = (const float*)d_in[4];
    const float* pw1 = (const float*)d_in[5];  const float* pb1 = (const float*)d_in[6];
    const float* pw2 = (const float*)d_in[7];  const float* pb2 = (const float*)d_in[8];
    const float* fw1 = (const float*)d_in[9];  const float* fb1 = (const float*)d_in[10];
    const float* fw2 = (const float*)d_in[11]; const float* fb2 = (const float*)d_in[12];
    const float* fw3 = (const float*)d_in[13]; const float* fb3 = (const float*)d_in[14];
    const float* dw  = (const float*)d_in[15]; const float* db  = (const float*)d_in[16];
    const float* rw1 = (const float*)d_in[17]; const float* rb1 = (const float*)d_in[18];
    const float* rw2 = (const float*)d_in[19]; const float* rb2 = (const float*)d_in[20];

    float*        out     = (float*)d_out;
    int*          wsidx   = (int*)d_ws;
    float*        wssums  = (float*)((char*)d_ws + WS_SUMS_OFF);
    unsigned int* wspcnt  = (unsigned int*)((char*)d_ws + WS_PCNT_OFF);
    unsigned int* wspsta  = (unsigned int*)((char*)d_ws + WS_PSTART_OFF);
    unsigned int* wspcur  = (unsigned int*)((char*)d_ws + WS_PCUR_OFF);
    unsigned int* wsqcnt  = (unsigned int*)((char*)d_ws + WS_QCNT_OFF);
    unsigned int* wsqsta  = (unsigned int*)((char*)d_ws + WS_QSTART_OFF);
    unsigned int* wsqcur  = (unsigned int*)((char*)d_ws + WS_QCUR_OFF);
    int*          wsqid   = (int*)((char*)d_ws + WS_QID_OFF);
    float4*       wspg    = (float4*)((char*)d_ws + WS_PG_OFF);
    int*          wspid   = (int*)((char*)d_ws + WS_PID_OFF);
    unsigned int* wswp    = (unsigned int*)((char*)d_ws + WS_WP_OFF);
    float*        wstex   = (float*)((char*)d_ws + WS_TEX_OFF);

    const size_t need_tex = WS_TEX_OFF + (size_t)6 * HWSZ * 32 * 4;
    const int use_t = (ws_size >= need_tex) ? 1 : 0;

    PackArgs pa;
    pa.src[0] = pw1; pa.off[0] = WP_PW1; pa.din[0] = 59;  pa.dout[0] = 64;
    pa.src[1] = pw2; pa.off[1] = WP_PW2; pa.din[1] = 64;  pa.dout[1] = 32;
    pa.src[2] = fw1; pa.off[2] = WP_FW1; pa.din[2] = 64;  pa.dout[2] = 128;
    pa.src[3] = fw2; pa.off[3] = WP_FW2; pa.din[3] = 128; pa.dout[3] = 128;
    pa.src[4] = fw3; pa.off[4] = WP_FW3; pa.din[4] = 128; pa.dout[4] = 128;
    pa.src[5] = dw;  pa.off[5] = WP_DW;  pa.din[5] = 128; pa.dout[5] = 1;
    pa.src[6] = rw1; pa.off[6] = WP_RW1; pa.din[6] = 155; pa.dout[6] = 64;
    pa.src[7] = rw2; pa.off[7] = WP_RW2; pa.din[7] = 64;  pa.dout[7] = 32;

    hipMemsetAsync((char*)d_ws + WS_PCNT_OFF, 0, WS_QSTART_OFF - WS_PCNT_OFF, stream);
    k_pack<<<dim3(32, 8), 256, 0, stream>>>(pa, wswp);
    if (use_t) k_transpose<<<6 * 256, 256, 0, stream>>>(tex, wstex);
    k_gcount<<<(NB*PP + 255)/256, 256, 0, stream>>>(pts, wspcnt);
    k_qcount<<<NQ/256, 256, 0, stream>>>(coords, wsqcnt);
    k_scan<<<1, 1024, 0, stream>>>(wspcnt, wspsta, wspcur, PP);
    k_scan<<<1, 1024, 0, stream>>>(wsqcnt, wsqsta, wsqcur, MQ);
    k_gscatter<<<(NB*PP + 255)/256, 256, 0, stream>>>(pts, wspcur, wspg, wspid);
    k_qscatter<<<NQ/256, 256, 0, stream>>>(coords, wsqcur, wsqid);
    k_knn_cell<<<NB*GC, 256, 0, stream>>>(coords, wspsta, wspcnt, wspg, wspid,
                                          wsqsta, wsqcnt, wsqid,
                                          out + OUT_DIST_OFF, wsidx);
    k_sums<<<8, 1024, 0, stream>>>(out + OUT_DIST_OFF, wssums);
    k_main<<<NQ / 64, 1024, 0, stream>>>(coords, dirs, pts, tex, wstex, emb,
                                         wswp, pb1, pb2, fb1, fb2, fb3, db, rb1, rb2,
                                         wsidx, out + OUT_DIST_OFF, wssums, out, use_t);
}

// Round 12
// 382.886 us; speedup vs baseline: 1.6139x; 1.6139x over previous
//
#include <hip/hip_runtime.h>
#include <float.h>
#include <math.h>

#define NB 2
#define MQ 16384
#define NQ (NB*MQ)          // 32768 queries
#define PP 5023
#define KNN 4
#define HPX 256
#define HWSZ (HPX*HPX)      // 65536
#define GD 12               // grid dim
#define GC (GD*GD*GD)       // 1728 cells
#define CAND_MAX 1024

// output layout (floats): densities[NQ], rgb[NQ*32], dist[NQ*4]
#define OUT_RGB_OFF  ((size_t)NQ)
#define OUT_DIST_OFF ((size_t)NQ + (size_t)NQ*32)

// workspace layout (bytes)
#define WS_SUMS_OFF   ((size_t)0x80000)
#define WS_PCNT_OFF   ((size_t)0x81000)
#define WS_PSTART_OFF ((size_t)0x85000)
#define WS_PCUR_OFF   ((size_t)0x89000)
#define WS_QCNT_OFF   ((size_t)0x8D000)
#define WS_QSTART_OFF ((size_t)0x91000)
#define WS_QCUR_OFF   ((size_t)0x95000)
#define WS_QID_OFF    ((size_t)0x99000)      // 32768*4 = 128 KB
#define WS_PG_OFF     ((size_t)0xC0000)      // 2*5023*16
#define WS_PID_OFF    ((size_t)0xF0000)      // 2*5023*4
#define WS_WP_OFF     ((size_t)0x100000)     // 29504 u32
#define WS_TEX_OFF    ((size_t)0x120000)     // 48 MB transposed tex

// packed-weight sub-offsets (u32 units)
#define WP_PW1 0
#define WP_PW2 1920
#define WP_FW1 2944
#define WP_FW2 7040
#define WP_FW3 15232
#define WP_DW  23424
#define WP_RW1 23488
#define WP_RW2 28480

typedef __attribute__((ext_vector_type(2))) _Float16 half2v;

static __device__ __forceinline__ unsigned int pk2(float a, float b) {
    half2v h; h[0] = (_Float16)a; h[1] = (_Float16)b;   // RNE converts
    return __builtin_bit_cast(unsigned int, h);
}
static __device__ __forceinline__ float2 upk(unsigned int u) {
    half2v h = __builtin_bit_cast(half2v, u);
    return make_float2((float)h[0], (float)h[1]);
}
static __device__ __forceinline__ float dot2(unsigned int a, unsigned int b, float c) {
    return __builtin_amdgcn_fdot2(__builtin_bit_cast(half2v, a),
                                  __builtin_bit_cast(half2v, b), c, false);
}
static __device__ __forceinline__ int cell_of(float x) {
    int g = (int)(x * (float)GD);
    return (g < 0) ? 0 : ((g > GD-1) ? GD-1 : g);
}

// ------------------------------------------------------------------
struct PackArgs {
    const float* src[8];
    int off[8]; int din[8]; int dout[8];
};
__global__ __launch_bounds__(256) void k_pack(PackArgs a, unsigned int* wp) {
    const int mid = blockIdx.y;
    const int idx = blockIdx.x * 256 + threadIdx.x;
    const int DIN = a.din[mid], DOUT = a.dout[mid];
    const int din2 = (DIN + 1) >> 1;
    if (idx >= din2 * DOUT) return;
    const int i2 = idx / DOUT, j = idx - i2 * DOUT;
    const float* s = a.src[mid];
    const float lo = s[(2*i2) * DOUT + j];
    const float hi = (2*i2 + 1 < DIN) ? s[(2*i2 + 1) * DOUT + j] : 0.f;
    wp[a.off[mid] + idx] = pk2(lo, hi);
}

// ------------------------------------------------------------------
__global__ __launch_bounds__(256) void k_transpose(const float* __restrict__ src,
                                                   float* __restrict__ dst) {
    const int tid = threadIdx.x;
    const int b = blockIdx.x;            // 6*256 blocks
    const int n3 = b >> 8;
    const int hw = ((b & 255) << 8) + tid;
    const float* s = src + (size_t)n3 * 32 * HWSZ + hw;
    float v[32];
#pragma unroll
    for (int c = 0; c < 32; ++c) v[c] = s[(size_t)c * HWSZ];
    float4* d = (float4*)(dst + ((size_t)n3 * HWSZ + hw) * 32);
#pragma unroll
    for (int c = 0; c < 8; ++c) d[c] = make_float4(v[4*c], v[4*c+1], v[4*c+2], v[4*c+3]);
}

// ------------------------------------------------------------------
// bucket builds
__global__ __launch_bounds__(256) void k_gcount(const float* __restrict__ pts,
                                                unsigned int* __restrict__ cnt) {
    const int i = blockIdx.x * 256 + threadIdx.x;
    if (i >= NB * PP) return;
    const int n = (i >= PP) ? 1 : 0;
    const float px = pts[3*i], py = pts[3*i+1], pz = pts[3*i+2];
    const int c = (cell_of(pz)*GD + cell_of(py))*GD + cell_of(px);
    atomicAdd(&cnt[n*GC + c], 1u);
}
__global__ __launch_bounds__(256) void k_qcount(const float* __restrict__ coords,
                                                unsigned int* __restrict__ cnt) {
    const int q = blockIdx.x * 256 + threadIdx.x;
    if (q >= NQ) return;
    const int n = q >> 14;
    const float cx = coords[3*q], cy = coords[3*q+1], cz = coords[3*q+2];
    const int c = (cell_of(cz)*GD + cell_of(cy))*GD + cell_of(cx);
    atomicAdd(&cnt[n*GC + c], 1u);
}

__global__ __launch_bounds__(1024) void k_scan(const unsigned int* __restrict__ cnt,
                                               unsigned int* __restrict__ start,
                                               unsigned int* __restrict__ cursor,
                                               int stride) {
    __shared__ unsigned int sc[1024];
    const int t = threadIdx.x;
#pragma unroll 1
    for (int n = 0; n < 2; ++n) {
        const unsigned int* c = cnt + n*GC;
        unsigned int a = (2*t   < GC) ? c[2*t]   : 0u;
        unsigned int b = (2*t+1 < GC) ? c[2*t+1] : 0u;
        unsigned int s = a + b;
        sc[t] = s;
        __syncthreads();
        for (int off = 1; off < 1024; off <<= 1) {
            unsigned int v = (t >= off) ? sc[t - off] : 0u;
            __syncthreads();
            sc[t] += v;
            __syncthreads();
        }
        unsigned int excl = sc[t] - s;
        unsigned int base = n * stride;
        if (2*t < GC)   { start[n*GC + 2*t]   = base + excl;
                          cursor[n*GC + 2*t]  = base + excl; }
        if (2*t+1 < GC) { start[n*GC + 2*t+1] = base + excl + a;
                          cursor[n*GC + 2*t+1]= base + excl + a; }
        __syncthreads();
    }
}

__global__ __launch_bounds__(256) void k_gscatter(const float* __restrict__ pts,
                                                  unsigned int* __restrict__ cursor,
                                                  float4* __restrict__ pg,
                                                  int* __restrict__ pid) {
    const int i = blockIdx.x * 256 + threadIdx.x;
    if (i >= NB * PP) return;
    const int n = (i >= PP) ? 1 : 0;
    const int local = i - n * PP;
    const float px = pts[3*i], py = pts[3*i+1], pz = pts[3*i+2];
    const int c = (cell_of(pz)*GD + cell_of(py))*GD + cell_of(px);
    const unsigned int pos = atomicAdd(&cursor[n*GC + c], 1u);
    pg[pos] = make_float4(px, py, pz, fmaf(px, px, fmaf(py, py, pz*pz)));
    pid[pos] = local;
}
__global__ __launch_bounds__(256) void k_qscatter(const float* __restrict__ coords,
                                                  unsigned int* __restrict__ cursor,
                                                  int* __restrict__ qid) {
    const int q = blockIdx.x * 256 + threadIdx.x;
    if (q >= NQ) return;
    const int n = q >> 14;
    const float cx = coords[3*q], cy = coords[3*q+1], cz = coords[3*q+2];
    const int c = (cell_of(cz)*GD + cell_of(cy))*GD + cell_of(cx);
    const unsigned int pos = atomicAdd(&cursor[n*GC + c], 1u);
    qid[pos] = q;
}

// ------------------------------------------------------------------
// KNN (proven R10): one block per (n,cell); ring<=2 candidates in LDS;
// 16-lane group per query; exact (d2,idx) top-4 + butterfly merge.
__global__ __launch_bounds__(256) void k_knn_cell(
    const float* __restrict__ coords,
    const unsigned int* __restrict__ pstart, const unsigned int* __restrict__ pcnt,
    const float4* __restrict__ pg, const int* __restrict__ pid,
    const unsigned int* __restrict__ qstart, const unsigned int* __restrict__ qcnt,
    const int* __restrict__ qid,
    float* __restrict__ odist, int* __restrict__ oidx)
{
    __shared__ float4 cand[CAND_MAX];        // 16 KB
    __shared__ int    cidx[CAND_MAX];        // 4 KB
    __shared__ unsigned int cs[125], cc[125], co[126];
    const int tid = threadIdx.x;
    const int bid = blockIdx.x;              // 2*GC
    const int n = bid / GC, c = bid % GC;
    const unsigned int qn = qcnt[n*GC + c];
    if (qn == 0) return;
    const int gz = c / (GD*GD), gy = (c / GD) % GD, gx = c % GD;

    const int x0 = max(gx-2,0), x1 = min(gx+2,GD-1), nx = x1-x0+1;
    const int y0 = max(gy-2,0), y1 = min(gy+2,GD-1), ny = y1-y0+1;
    const int z0 = max(gz-2,0), z1 = min(gz+2,GD-1), nz = z1-z0+1;
    const int ncell = nx*ny*nz;

    if (tid < ncell) {
        const int xx = x0 + tid % nx;
        const int yy = y0 + (tid / nx) % ny;
        const int zz = z0 + tid / (nx*ny);
        const int cid = n*GC + (zz*GD + yy)*GD + xx;
        cs[tid] = pstart[cid];
        cc[tid] = pcnt[cid];
    }
    __syncthreads();
    if (tid == 0) {
        unsigned int acc = 0;
        co[0] = 0;
        for (int t = 0; t < ncell; ++t) { acc += cc[t]; co[t+1] = acc; }
    }
    __syncthreads();
    const unsigned int total = co[ncell];
    const bool ovf = (total > CAND_MAX);
    if (!ovf) {
#pragma unroll 1
        for (int t = 0; t < ncell; ++t) {
            const unsigned int m = cc[t];
            if (tid < (int)m) {
                cand[co[t] + tid] = pg[cs[t] + tid];
                cidx[co[t] + tid] = pid[cs[t] + tid];
            }
        }
    }
    __syncthreads();

    const float w = 1.0f / (float)GD;
    const float thresh = 4.f * w * w * 0.999f;
    const int grp = tid >> 4, l16 = tid & 15;
    const unsigned int qs = qstart[n*GC + c];

#define INS4(d, i) { \
        bool L3 = ((d) < bd3) || ((d) == bd3 && (i) < bi3); \
        bool L2 = ((d) < bd2) || ((d) == bd2 && (i) < bi2); \
        bool L1 = ((d) < bd1) || ((d) == bd1 && (i) < bi1); \
        bool L0 = ((d) < bd0) || ((d) == bd0 && (i) < bi0); \
        bd3 = L3 ? (L2 ? bd2 : (d)) : bd3;  bi3 = L3 ? (L2 ? bi2 : (i)) : bi3; \
        bd2 = L2 ? (L1 ? bd1 : (d)) : bd2;  bi2 = L2 ? (L1 ? bi1 : (i)) : bi2; \
        bd1 = L1 ? (L0 ? bd0 : (d)) : bd1;  bi1 = L1 ? (L0 ? bi0 : (i)) : bi1; \
        bd0 = L0 ? (d) : bd0;               bi0 = L0 ? (i) : bi0; }

#define MERGE16() { \
        float bd[4] = { bd0, bd1, bd2, bd3 }; \
        int   bi[4] = { bi0, bi1, bi2, bi3 }; \
        for (int mask = 1; mask < 16; mask <<= 1) { \
            float od[4]; int oi[4]; \
            for (int j = 0; j < 4; ++j) { od[j] = __shfl_xor(bd[j], mask); \
                                          oi[j] = __shfl_xor(bi[j], mask); } \
            float e[4]; int ei[4]; \
            for (int j = 0; j < 4; ++j) { \
                float ad = bd[j], xd = od[3-j]; \
                int   ai = bi[j], xi = oi[3-j]; \
                bool ta = (ad < xd) || (ad == xd && ai < xi); \
                e[j] = ta ? ad : xd; ei[j] = ta ? ai : xi; \
            } \
            { bool sw = (e[2] < e[0]) || (e[2] == e[0] && ei[2] < ei[0]); \
              if (sw) { float td=e[0]; e[0]=e[2]; e[2]=td; int ti=ei[0]; ei[0]=ei[2]; ei[2]=ti; } } \
            { bool sw = (e[3] < e[1]) || (e[3] == e[1] && ei[3] < ei[1]); \
              if (sw) { float td=e[1]; e[1]=e[3]; e[3]=td; int ti=ei[1]; ei[1]=ei[3]; ei[3]=ti; } } \
            { bool sw = (e[1] < e[0]) || (e[1] == e[0] && ei[1] < ei[0]); \
              if (sw) { float td=e[0]; e[0]=e[1]; e[1]=td; int ti=ei[0]; ei[0]=ei[1]; ei[1]=ti; } } \
            { bool sw = (e[3] < e[2]) || (e[3] == e[2] && ei[3] < ei[2]); \
              if (sw) { float td=e[2]; e[2]=e[3]; e[3]=td; int ti=ei[2]; ei[2]=ei[3]; ei[3]=ti; } } \
            for (int j = 0; j < 4; ++j) { bd[j] = e[j]; bi[j] = ei[j]; } \
        } \
        bd0 = bd[0]; bd1 = bd[1]; bd2 = bd[2]; bd3 = bd[3]; \
        bi0 = bi[0]; bi1 = bi[1]; bi2 = bi[2]; bi3 = bi[3]; }

#pragma unroll 1
    for (unsigned int qb = 0; qb < qn; qb += 16) {
        const unsigned int qi = qb + grp;
        if (qi >= qn) continue;
        const int q = qid[qs + qi];
        const float cx = coords[3*q], cy = coords[3*q+1], cz = coords[3*q+2];
        const float ccq = fmaf(cx, cx, fmaf(cy, cy, cz*cz));

        float bd0 = FLT_MAX, bd1 = FLT_MAX, bd2 = FLT_MAX, bd3 = FLT_MAX;
        int   bi0 = 0x7fffffff, bi1 = 0x7fffffff, bi2 = 0x7fffffff, bi3 = 0x7fffffff;

        if (!ovf) {
#pragma unroll 1
            for (unsigned int j = l16; j < total; j += 16) {
                const float4 P = cand[j];
                const int i = cidx[j];
                const float dt = fmaf(cx, P.x, fmaf(cy, P.y, cz * P.z));
                const float d = fmaf(-2.0f, dt, ccq + P.w);
                INS4(d, i)
            }
            MERGE16()
        }
        if (ovf || !(bd3 < thresh)) {
            bd0 = bd1 = bd2 = bd3 = FLT_MAX;
            bi0 = bi1 = bi2 = bi3 = 0x7fffffff;
#pragma unroll 1
            for (int j = l16; j < PP; j += 16) {
                const float4 P = pg[n*PP + j];
                const int i = pid[n*PP + j];
                const float dt = fmaf(cx, P.x, fmaf(cy, P.y, cz * P.z));
                const float d = fmaf(-2.0f, dt, ccq + P.w);
                INS4(d, i)
            }
            MERGE16()
        }
        if (l16 == 0) {
            *(float4*)(odist + (size_t)q*4) = make_float4(bd0, bd1, bd2, bd3);
            *(int4*)(oidx + (size_t)q*4)    = make_int4(bi0, bi1, bi2, bi3);
        }
    }
#undef INS4
#undef MERGE16
}

// ------------------------------------------------------------------
__global__ __launch_bounds__(1024) void k_sums(const float* __restrict__ dist,
                                               float* __restrict__ sums) {
    const int b = blockIdx.x;            // n*4+k, 8 blocks
    const int n = b >> 2, k = b & 3;
    float s = 0.f;
    for (int m = threadIdx.x; m < MQ; m += 1024)
        s += 1.0f / dist[((size_t)n * MQ + m) * 4 + k];
    __shared__ float red[1024];
    red[threadIdx.x] = s;
    __syncthreads();
    for (int off = 512; off > 0; off >>= 1) {
        if (threadIdx.x < off) red[threadIdx.x] += red[threadIdx.x + off];
        __syncthreads();
    }
    if (threadIdx.x == 0) sums[b] = red[0];
}

// ------------------------------------------------------------------
// packed gemv (R7-proven): activations f16x2 from LDS (col=lane), weights
// f16x2 via wave-uniform s_load stream from global. VGPR ~20, no spill.
template<int DIN2, int DOUT, int TILE>
__device__ __forceinline__ void gemv_p(const unsigned int* __restrict__ Xp, int lane,
                                       const unsigned int* __restrict__ Wp,
                                       const float* __restrict__ bias,
                                       int j0, float (&acc)[TILE]) {
#pragma unroll
    for (int u = 0; u < TILE; ++u) acc[u] = bias[j0 + u];
#pragma unroll
    for (int i2 = 0; i2 < DIN2; ++i2) {
        const unsigned int xv = Xp[i2 * 64 + lane];
        const unsigned int* wr = Wp + i2 * DOUT + j0;
#pragma unroll
        for (int u = 0; u < TILE; ++u) acc[u] = dot2(xv, wr[u], acc[u]);
    }
}

static __device__ __forceinline__ float harm_val(int h, float rx, float ry, float rz) {
    if (h >= 27) return 0.f;
    float v;
    if (h < 24) {
        int base = (h < 12) ? h : (h - 12);
        float rv = (base >> 2) == 0 ? rx : ((base >> 2) == 1 ? ry : rz);
        float e = rv * (float)(1 << (base & 3));
        v = (h < 12) ? sinf(e) : cosf(e);
    } else {
        v = (h == 24) ? rx : ((h == 25) ? ry : rz);
    }
    return v;
}

// ------------------------------------------------------------------
// main fused kernel (R7-proven, 135 us): all 4 neighbors concurrent across
// waves; scalar wv; weights streamed via s_load; LDS 62 KB; VGPR ~20.
__global__ __launch_bounds__(1024, 2) void k_main(
    const float* __restrict__ coords, const float* __restrict__ dirs,
    const float* __restrict__ pts, const float* __restrict__ tex_raw,
    const float* __restrict__ tex_t, const float* __restrict__ emb,
    const unsigned int* __restrict__ wp,
    const float* __restrict__ pb1, const float* __restrict__ pb2,
    const float* __restrict__ fb1, const float* __restrict__ fb2,
    const float* __restrict__ fb3, const float* __restrict__ db,
    const float* __restrict__ rb1, const float* __restrict__ rb2,
    const int* __restrict__ idxbuf, const float* __restrict__ distbuf,
    const float* __restrict__ sums, float* __restrict__ out, int use_tex_t)
{
    __shared__ unsigned int S[248 * 64];   // 62 KB
    const int tid  = threadIdx.x;
    const int lane = tid & 63;
    const int wv   = __builtin_amdgcn_readfirstlane(tid >> 6);   // 0..15
    const int q0   = blockIdx.x * 64;
    const int n    = q0 >> 14;
    const int q    = q0 + lane;

    // ---------- phase 0: triplane sampling -> fp32 regs (2 ch/wave) ----------
    float tex_acc[2] = {0.f, 0.f};
    {
        const int g = wv;
        const float cx = coords[q*3+0], cy = coords[q*3+1], cz = coords[q*3+2];
#pragma unroll
        for (int pl = 0; pl < 3; ++pl) {
            float gx = (pl == 2) ? cz : cx;
            float gy = (pl == 0) ? cy : ((pl == 1) ? cz : cx);
            float x = (gx + 1.f) * 128.f - 0.5f;
            float y = (gy + 1.f) * 128.f - 0.5f;
            float x0f = floorf(x), y0f = floorf(y);
            float wx1 = x - x0f, wy1 = y - y0f;
            float wx0 = 1.f - wx1, wy0 = 1.f - wy1;
            int x0 = (int)x0f, y0 = (int)y0f;
            int n3 = n * 3 + pl;
            int  xs[4] = { x0, x0+1, x0,   x0+1 };
            int  ys[4] = { y0, y0,   y0+1, y0+1 };
            float wt[4] = { wx0*wy0, wx1*wy0, wx0*wy1, wx1*wy1 };
#pragma unroll
            for (int c = 0; c < 4; ++c) {
                int xi = xs[c], yi = ys[c];
                if (xi >= 0 && xi < HPX && yi >= 0 && yi < HPX) {
                    float wgt = wt[c];
                    if (use_tex_t) {
                        const float2 a = *(const float2*)(tex_t +
                            (((size_t)n3 * HWSZ + (size_t)yi * HPX + xi) * 32 + g * 2));
                        tex_acc[0] = fmaf(wgt, a.x, tex_acc[0]);
                        tex_acc[1] = fmaf(wgt, a.y, tex_acc[1]);
                    } else {
                        size_t base = ((size_t)(n3 * 32 + g * 2)) * HWSZ + (size_t)yi * HPX + xi;
                        tex_acc[0] = fmaf(wgt, tex_raw[base], tex_acc[0]);
                        tex_acc[1] = fmaf(wgt, tex_raw[base + HWSZ], tex_acc[1]);
                    }
                }
            }
        }
        tex_acc[0] *= (1.f / 3.f); tex_acc[1] *= (1.f / 3.f);
    }

    const int kk  = wv & 3;      // neighbor index this wave handles
    const int prt = wv >> 2;     // 0..3 part / j-slice

    // ---------- phase A: build x59 for ALL 4 neighbors (rows kk*30 + r) ----------
    {
        const int id = idxbuf[(size_t)q*4 + kk];
        const int rb = kk * 30;
        if (prt < 2) {
#pragma unroll
            for (int t = 0; t < 2; ++t) {
                const float4 e = *(const float4*)(emb + (size_t)id * 32 + prt*16 + t*4 + 0)
                    , e2 = *(const float4*)(emb + (size_t)id * 32 + prt*16 + t*4 + 8);
                S[(rb + prt*8 + t*2    )*64 + lane] = pk2(e.x,  e.y);
                S[(rb + prt*8 + t*2 + 1)*64 + lane] = pk2(e.z,  e.w);
                S[(rb + prt*8 + t*2 + 4)*64 + lane] = pk2(e2.x, e2.y);
                S[(rb + prt*8 + t*2 + 5)*64 + lane] = pk2(e2.z, e2.w);
            }
        } else {
            const float cx = coords[q*3+0], cy = coords[q*3+1], cz = coords[q*3+2];
            const float nx = pts[((size_t)n*PP + id)*3 + 0];
            const float ny = pts[((size_t)n*PP + id)*3 + 1];
            const float nz = pts[((size_t)n*PP + id)*3 + 2];
            float rx = cx - nx, ry = cy - ny, rz = cz - nz;
            float nrm = sqrtf(fmaf(rx, rx, fmaf(ry, ry, rz*rz)));
            float inv = 1.f / fmaxf(nrm, 1e-12f);
            rx *= inv; ry *= inv; rz *= inv;
            const int pr0 = (prt == 2) ? 0 : 8;
            const int prn = (prt == 2) ? 8 : 6;
#pragma unroll
            for (int t = 0; t < 8; ++t) {
                if (t < prn) {
                    int pr = pr0 + t;
                    S[(rb + 16 + pr)*64 + lane] =
                        pk2(harm_val(2*pr, rx, ry, rz), harm_val(2*pr + 1, rx, ry, rz));
                }
            }
        }
    }
    __syncthreads();

    // ---------- phase B: p1 59->64 relu for all k; wave (kk, j0=prt*16) ----------
    {
        float acc[16];
        gemv_p<30, 64, 16>(S + (kk*30)*64, lane, wp + WP_PW1, pb1, prt * 16, acc);
        const int rb = 120 + kk*32 + prt*8;
#pragma unroll
        for (int u = 0; u < 8; ++u)
            S[(rb + u)*64 + lane] = pk2(fmaxf(acc[2*u], 0.f), fmaxf(acc[2*u+1], 0.f));
    }
    __syncthreads();

    // ---------- phase C: p2 64->32 for all k, wk-scaled -> rows kk*16 + r ----------
    {
        float acc[8];
        gemv_p<32, 32, 8>(S + (120 + kk*32)*64, lane, wp + WP_PW2, pb2, prt * 8, acc);
        const float dist = distbuf[(size_t)q*4 + kk];
        const float wk = (1.0f / dist) / sums[n*4 + kk];
        const int rb = kk*16 + prt*4;
#pragma unroll
        for (int u = 0; u < 4; ++u)
            S[(rb + u)*64 + lane] = pk2(wk * acc[2*u], wk * acc[2*u+1]);
    }
    __syncthreads();

    // ---------- phase D: feat -> rows 128..159 (tex 128..143, pts 144..159) ----------
    {
        S[(128 + wv)*64 + lane] = pk2(tex_acc[0], tex_acc[1]);
        float a = 0.f, b = 0.f;
#pragma unroll
        for (int k = 0; k < 4; ++k) {
            float2 v = upk(S[(k*16 + wv)*64 + lane]);
            a += v.x; b += v.y;
        }
        S[(144 + wv)*64 + lane] = pk2(a, b);
    }
    __syncthreads();

    // ---------- phase E: fw1 64->128 relu, rows 128..159 -> rows 0..63 ----------
    {
        float acc[8];
        gemv_p<32, 128, 8>(S + 128*64, lane, wp + WP_FW1, fb1, wv * 8, acc);
#pragma unroll
        for (int u = 0; u < 4; ++u)
            S[(4*wv + u)*64 + lane] = pk2(fmaxf(acc[2*u], 0.f), fmaxf(acc[2*u+1], 0.f));
    }
    __syncthreads();
    // ---------- phase F: fw2 128->128 relu, rows 0..63 -> rows 64..127 ----------
    {
        float acc[8];
        gemv_p<64, 128, 8>(S, lane, wp + WP_FW2, fb2, wv * 8, acc);
#pragma unroll
        for (int u = 0; u < 4; ++u)
            S[(64 + 4*wv + u)*64 + lane] = pk2(fmaxf(acc[2*u], 0.f), fmaxf(acc[2*u+1], 0.f));
    }
    __syncthreads();
    // ---------- phase G: fw3 128->128, rows 64..127 -> rows 0..63 ----------
    {
        float acc[8];
        gemv_p<64, 128, 8>(S + 64*64, lane, wp + WP_FW3, fb3, wv * 8, acc);
#pragma unroll
        for (int u = 0; u < 4; ++u)
            S[(4*wv + u)*64 + lane] = pk2(acc[2*u], acc[2*u+1]);
    }
    __syncthreads();
    // ---------- phase H: ray harm -> rows 128..141; density (wave 15) ----------
    {
        if (wv < 14) {
            float dx = dirs[q*3+0], dy = dirs[q*3+1], dz = dirs[q*3+2];
            float dn = sqrtf(fmaf(dx, dx, fmaf(dy, dy, dz*dz)));
            float inv = 1.f / fmaxf(dn, 1e-12f);
            dx *= inv; dy *= inv; dz *= inv;
            S[(128 + wv)*64 + lane] = pk2(harm_val(2*wv, dx, dy, dz),
                                          harm_val(2*wv + 1, dx, dy, dz));
        } else if (wv == 15) {
            float z = db[0];
            const unsigned int* dwp = wp + WP_DW;
#pragma unroll 1
            for (int i2 = 0; i2 < 64; ++i2) z = dot2(S[i2*64 + lane], dwp[i2], z);
            const float cx = coords[q*3+0], cy = coords[q*3+1], cz = coords[q*3+2];
            float selv = (cx > -1.f && cx < 1.f && cy > -1.f && cy < 1.f &&
                          cz > -1.f && cz < 1.f) ? 1.f : 0.f;
            float t10 = 10.f * z;
            float sp = (t10 > 20.f) ? t10 : log1pf(expf(t10));
            float raw = sp * 0.1f * selv;
            out[q] = 1.f - expf(-raw);
        }
    }
    __syncthreads();
    // ---------- phase I: rw1 155->64 relu; feat rows 0..63 + harm 128..141 -> 64..95 ----------
    {
        const int j0 = wv * 4;
        float acc[4];
        gemv_p<64, 64, 4>(S, lane, wp + WP_RW1, rb1, j0, acc);
#pragma unroll
        for (int t = 0; t < 14; ++t) {
            const unsigned int xv = S[(128 + t)*64 + lane];
            const unsigned int* wr = wp + WP_RW1 + (64 + t) * 64 + j0;
#pragma unroll
            for (int u = 0; u < 4; ++u) acc[u] = dot2(xv, wr[u], acc[u]);
        }
        S[(64 + 2*wv    )*64 + lane] = pk2(fmaxf(acc[0], 0.f), fmaxf(acc[1], 0.f));
        S[(64 + 2*wv + 1)*64 + lane] = pk2(fmaxf(acc[2], 0.f), fmaxf(acc[3], 0.f));
    }
    __syncthreads();
    // ---------- phase J: rw2 64->32, sigmoid on first 3; rows 64..95 -> out ----------
    {
        float acc[2];
        gemv_p<32, 32, 2>(S + 64*64, lane, wp + WP_RW2, rb2, wv * 2, acc);
#pragma unroll
        for (int u = 0; u < 2; ++u) {
            int j = wv*2 + u;
            float v = acc[u];
            if (j < 3) v = 1.002f * (1.f / (1.f + expf(-v))) - 0.001f;
            out[OUT_RGB_OFF + (size_t)q*32 + j] = v;
        }
    }
}

// ------------------------------------------------------------------
extern "C" void kernel_launch(void* const* d_in, const int* in_sizes, int n_in,
                              void* d_out, int out_size, void* d_ws, size_t ws_size,
                              hipStream_t stream) {
    (void)in_sizes; (void)n_in; (void)out_size;
    const float* coords = (const float*)d_in[0];
    const float* dirs   = (const float*)d_in[1];
    const float* pts    = (const float*)d_in[2];
    const float* tex    = (const float*)d_in[3];
    const float* emb    = (const float*)d_in[4];
    const float* pw1 = (const float*)d_in[5];  const float* pb1 = (const float*)d_in[6];
    const float* pw2 = (const float*)d_in[7];  const float* pb2 = (const float*)d_in[8];
    const float* fw1 = (const float*)d_in[9];  const float* fb1 = (const float*)d_in[10];
    const float* fw2 = (const float*)d_in[11]; const float* fb2 = (const float*)d_in[12];
    const float* fw3 = (const float*)d_in[13]; const float* fb3 = (const float*)d_in[14];
    const float* dw  = (const float*)d_in[15]; const float* db  = (const float*)d_in[16];
    const float* rw1 = (const float*)d_in[17]; const float* rb1 = (const float*)d_in[18];
    const float* rw2 = (const float*)d_in[19]; const float* rb2 = (const float*)d_in[20];

    float*        out     = (float*)d_out;
    int*          wsidx   = (int*)d_ws;
    float*        wssums  = (float*)((char*)d_ws + WS_SUMS_OFF);
    unsigned int* wspcnt  = (unsigned int*)((char*)d_ws + WS_PCNT_OFF);
    unsigned int* wspsta  = (unsigned int*)((char*)d_ws + WS_PSTART_OFF);
    unsigned int* wspcur  = (unsigned int*)((char*)d_ws + WS_PCUR_OFF);
    unsigned int* wsqcnt  = (unsigned int*)((char*)d_ws + WS_QCNT_OFF);
    unsigned int* wsqsta  = (unsigned int*)((char*)d_ws + WS_QSTART_OFF);
    unsigned int* wsqcur  = (unsigned int*)((char*)d_ws + WS_QCUR_OFF);
    int*          wsqid   = (int*)((char*)d_ws + WS_QID_OFF);
    float4*       wspg    = (float4*)((char*)d_ws + WS_PG_OFF);
    int*          wspid   = (int*)((char*)d_ws + WS_PID_OFF);
    unsigned int* wswp    = (unsigned int*)((char*)d_ws + WS_WP_OFF);
    float*        wstex   = (float*)((char*)d_ws + WS_TEX_OFF);

    const size_t need_tex = WS_TEX_OFF + (size_t)6 * HWSZ * 32 * 4;
    const int use_t = (ws_size >= need_tex) ? 1 : 0;

    PackArgs pa;
    pa.src[0] = pw1; pa.off[0] = WP_PW1; pa.din[0] = 59;  pa.dout[0] = 64;
    pa.src[1] = pw2; pa.off[1] = WP_PW2; pa.din[1] = 64;  pa.dout[1] = 32;
    pa.src[2] = fw1; pa.off[2] = WP_FW1; pa.din[2] = 64;  pa.dout[2] = 128;
    pa.src[3] = fw2; pa.off[3] = WP_FW2; pa.din[3] = 128; pa.dout[3] = 128;
    pa.src[4] = fw3; pa.off[4] = WP_FW3; pa.din[4] = 128; pa.dout[4] = 128;
    pa.src[5] = dw;  pa.off[5] = WP_DW;  pa.din[5] = 128; pa.dout[5] = 1;
    pa.src[6] = rw1; pa.off[6] = WP_RW1; pa.din[6] = 155; pa.dout[6] = 64;
    pa.src[7] = rw2; pa.off[7] = WP_RW2; pa.din[7] = 64;  pa.dout[7] = 32;

    hipMemsetAsync((char*)d_ws + WS_PCNT_OFF, 0, WS_QSTART_OFF - WS_PCNT_OFF, stream);
    k_pack<<<dim3(32, 8), 256, 0, stream>>>(pa, wswp);
    if (use_t) k_transpose<<<6 * 256, 256, 0, stream>>>(tex, wstex);
    k_gcount<<<(NB*PP + 255)/256, 256, 0, stream>>>(pts, wspcnt);
    k_qcount<<<NQ/256, 256, 0, stream>>>(coords, wsqcnt);
    k_scan<<<1, 1024, 0, stream>>>(wspcnt, wspsta, wspcur, PP);
    k_scan<<<1, 1024, 0, stream>>>(wsqcnt, wsqsta, wsqcur, MQ);
    k_gscatter<<<(NB*PP + 255)/256, 256, 0, stream>>>(pts, wspcur, wspg, wspid);
    k_qscatter<<<NQ/256, 256, 0, stream>>>(coords, wsqcur, wsqid);
    k_knn_cell<<<NB*GC, 256, 0, stream>>>(coords, wspsta, wspcnt, wspg, wspid,
                                          wsqsta, wsqcnt, wsqid,
                                          out + OUT_DIST_OFF, wsidx);
    k_sums<<<8, 1024, 0, stream>>>(out + OUT_DIST_OFF, wssums);
    k_main<<<NQ / 64, 1024, 0, stream>>>(coords, dirs, pts, tex, wstex, emb,
                                         wswp, pb1, pb2, fb1, fb2, fb3, db, rb1, rb2,
                                         wsidx, out + OUT_DIST_OFF, wssums, out, use_t);
}

// Round 13
// 301.162 us; speedup vs baseline: 2.0518x; 1.2714x over previous
//
#include <hip/hip_runtime.h>
#include <float.h>
#include <math.h>

#define NB 2
#define MQ 16384
#define NQ (NB*MQ)          // 32768 queries
#define PP 5023
#define KNN 4
#define HPX 256
#define HWSZ (HPX*HPX)      // 65536
#define GD 12               // grid dim
#define GC (GD*GD*GD)       // 1728 cells
#define CAND_MAX 1024

// output layout (floats): densities[NQ], rgb[NQ*32], dist[NQ*4]
#define OUT_RGB_OFF  ((size_t)NQ)
#define OUT_DIST_OFF ((size_t)NQ + (size_t)NQ*32)

// workspace layout (bytes)
#define WS_SUMS_OFF   ((size_t)0x80000)
#define WS_PCNT_OFF   ((size_t)0x81000)
#define WS_PSTART_OFF ((size_t)0x85000)
#define WS_PCUR_OFF   ((size_t)0x89000)
#define WS_QCNT_OFF   ((size_t)0x8D000)
#define WS_QSTART_OFF ((size_t)0x91000)
#define WS_QCUR_OFF   ((size_t)0x95000)
#define WS_QID_OFF    ((size_t)0x99000)      // 32768*4 = 128 KB
#define WS_PG_OFF     ((size_t)0xC0000)      // 2*5023*16
#define WS_PID_OFF    ((size_t)0xF0000)      // 2*5023*4
#define WS_WP_OFF     ((size_t)0x100000)     // 29504 u32
#define WS_TEX_OFF    ((size_t)0x120000)     // 48 MB transposed tex

// packed-weight sub-offsets (u32 units)
#define WP_PW1 0
#define WP_PW2 1920
#define WP_FW1 2944
#define WP_FW2 7040
#define WP_FW3 15232
#define WP_DW  23424
#define WP_RW1 23488
#define WP_RW2 28480

typedef __attribute__((ext_vector_type(2))) _Float16 half2v;

static __device__ __forceinline__ unsigned int pk2(float a, float b) {
    half2v h; h[0] = (_Float16)a; h[1] = (_Float16)b;   // RNE converts
    return __builtin_bit_cast(unsigned int, h);
}
static __device__ __forceinline__ float2 upk(unsigned int u) {
    half2v h = __builtin_bit_cast(half2v, u);
    return make_float2((float)h[0], (float)h[1]);
}
static __device__ __forceinline__ float dot2(unsigned int a, unsigned int b, float c) {
    return __builtin_amdgcn_fdot2(__builtin_bit_cast(half2v, a),
                                  __builtin_bit_cast(half2v, b), c, false);
}
static __device__ __forceinline__ int cell_of(float x) {
    int g = (int)(x * (float)GD);
    return (g < 0) ? 0 : ((g > GD-1) ? GD-1 : g);
}

// ------------------------------------------------------------------
struct PackArgs {
    const float* src[8];
    int off[8]; int din[8]; int dout[8];
};
__global__ __launch_bounds__(256) void k_pack(PackArgs a, unsigned int* wp) {
    const int mid = blockIdx.y;
    const int idx = blockIdx.x * 256 + threadIdx.x;
    const int DIN = a.din[mid], DOUT = a.dout[mid];
    const int din2 = (DIN + 1) >> 1;
    if (idx >= din2 * DOUT) return;
    const int i2 = idx / DOUT, j = idx - i2 * DOUT;
    const float* s = a.src[mid];
    const float lo = s[(2*i2) * DOUT + j];
    const float hi = (2*i2 + 1 < DIN) ? s[(2*i2 + 1) * DOUT + j] : 0.f;
    wp[a.off[mid] + idx] = pk2(lo, hi);
}

// ------------------------------------------------------------------
__global__ __launch_bounds__(256) void k_transpose(const float* __restrict__ src,
                                                   float* __restrict__ dst) {
    const int tid = threadIdx.x;
    const int b = blockIdx.x;            // 6*256 blocks
    const int n3 = b >> 8;
    const int hw = ((b & 255) << 8) + tid;
    const float* s = src + (size_t)n3 * 32 * HWSZ + hw;
    float v[32];
#pragma unroll
    for (int c = 0; c < 32; ++c) v[c] = s[(size_t)c * HWSZ];
    float4* d = (float4*)(dst + ((size_t)n3 * HWSZ + hw) * 32);
#pragma unroll
    for (int c = 0; c < 8; ++c) d[c] = make_float4(v[4*c], v[4*c+1], v[4*c+2], v[4*c+3]);
}

// ------------------------------------------------------------------
// fused bucket build: points then queries
__global__ __launch_bounds__(256) void k_count(const float* __restrict__ pts,
                                               const float* __restrict__ coords,
                                               unsigned int* __restrict__ pcnt,
                                               unsigned int* __restrict__ qcnt) {
    const int i = blockIdx.x * 256 + threadIdx.x;
    if (i < NB * PP) {
        const int n = (i >= PP) ? 1 : 0;
        const float px = pts[3*i], py = pts[3*i+1], pz = pts[3*i+2];
        const int c = (cell_of(pz)*GD + cell_of(py))*GD + cell_of(px);
        atomicAdd(&pcnt[n*GC + c], 1u);
    } else if (i - NB*PP < NQ) {
        const int q = i - NB*PP;
        const int n = q >> 14;
        const float cx = coords[3*q], cy = coords[3*q+1], cz = coords[3*q+2];
        const int c = (cell_of(cz)*GD + cell_of(cy))*GD + cell_of(cx);
        atomicAdd(&qcnt[n*GC + c], 1u);
    }
}

__global__ __launch_bounds__(1024) void k_scan2(const unsigned int* __restrict__ pcnt,
                                                unsigned int* __restrict__ psta,
                                                unsigned int* __restrict__ pcur,
                                                const unsigned int* __restrict__ qcnt,
                                                unsigned int* __restrict__ qsta,
                                                unsigned int* __restrict__ qcur) {
    __shared__ unsigned int sc[1024];
    const int t = threadIdx.x;
#pragma unroll 1
    for (int which = 0; which < 2; ++which) {
        const unsigned int* cnt = which ? qcnt : pcnt;
        unsigned int* start  = which ? qsta : psta;
        unsigned int* cursor = which ? qcur : pcur;
        const int stride = which ? MQ : PP;
#pragma unroll 1
        for (int n = 0; n < 2; ++n) {
            const unsigned int* c = cnt + n*GC;
            unsigned int a = (2*t   < GC) ? c[2*t]   : 0u;
            unsigned int b = (2*t+1 < GC) ? c[2*t+1] : 0u;
            unsigned int s = a + b;
            sc[t] = s;
            __syncthreads();
            for (int off = 1; off < 1024; off <<= 1) {
                unsigned int v = (t >= off) ? sc[t - off] : 0u;
                __syncthreads();
                sc[t] += v;
                __syncthreads();
            }
            unsigned int excl = sc[t] - s;
            unsigned int base = n * stride;
            if (2*t < GC)   { start[n*GC + 2*t]   = base + excl;
                              cursor[n*GC + 2*t]  = base + excl; }
            if (2*t+1 < GC) { start[n*GC + 2*t+1] = base + excl + a;
                              cursor[n*GC + 2*t+1]= base + excl + a; }
            __syncthreads();
        }
    }
}

__global__ __launch_bounds__(256) void k_scatter(const float* __restrict__ pts,
                                                 const float* __restrict__ coords,
                                                 unsigned int* __restrict__ pcur,
                                                 unsigned int* __restrict__ qcur,
                                                 float4* __restrict__ pg,
                                                 int* __restrict__ pid,
                                                 int* __restrict__ qid) {
    const int i = blockIdx.x * 256 + threadIdx.x;
    if (i < NB * PP) {
        const int n = (i >= PP) ? 1 : 0;
        const int local = i - n * PP;
        const float px = pts[3*i], py = pts[3*i+1], pz = pts[3*i+2];
        const int c = (cell_of(pz)*GD + cell_of(py))*GD + cell_of(px);
        const unsigned int pos = atomicAdd(&pcur[n*GC + c], 1u);
        pg[pos] = make_float4(px, py, pz, fmaf(px, px, fmaf(py, py, pz*pz)));
        pid[pos] = local;
    } else if (i - NB*PP < NQ) {
        const int q = i - NB*PP;
        const int n = q >> 14;
        const float cx = coords[3*q], cy = coords[3*q+1], cz = coords[3*q+2];
        const int c = (cell_of(cz)*GD + cell_of(cy))*GD + cell_of(cx);
        const unsigned int pos = atomicAdd(&qcur[n*GC + c], 1u);
        qid[pos] = q;
    }
}

// ------------------------------------------------------------------
// KNN v9: ring<=2 candidates = <=25 x-contiguous pg ranges; staged
// candidate-parallel (binary search over row prefix). Exact selection.
__global__ __launch_bounds__(256) void k_knn_cell(
    const float* __restrict__ coords,
    const unsigned int* __restrict__ pstart, const unsigned int* __restrict__ pcnt,
    const float4* __restrict__ pg, const int* __restrict__ pid,
    const unsigned int* __restrict__ qstart, const unsigned int* __restrict__ qcnt,
    const int* __restrict__ qid,
    float* __restrict__ odist, int* __restrict__ oidx)
{
    __shared__ float4 cand[CAND_MAX];        // 16 KB
    __shared__ int    cidx[CAND_MAX];        // 4 KB
    __shared__ unsigned int rs[25], ro[26];
    const int tid = threadIdx.x;
    const int bid = blockIdx.x;              // 2*GC
    const int n = bid / GC, c = bid % GC;
    const unsigned int qn = qcnt[n*GC + c];
    if (qn == 0) return;
    const int gz = c / (GD*GD), gy = (c / GD) % GD, gx = c % GD;

    const int x0 = max(gx-2,0), x1 = min(gx+2,GD-1);
    const int y0 = max(gy-2,0), y1 = min(gy+2,GD-1), ny = y1-y0+1;
    const int z0 = max(gz-2,0), z1 = min(gz+2,GD-1), nz = z1-z0+1;
    const int nrow = ny*nz;                  // <= 25

    __shared__ unsigned int rcnt[25];
    if (tid < nrow) {
        const int yy = y0 + tid % ny;
        const int zz = z0 + tid / ny;
        const int c0 = n*GC + (zz*GD + yy)*GD + x0;
        const int c1 = n*GC + (zz*GD + yy)*GD + x1;
        const unsigned int s = pstart[c0];
        rs[tid]   = s;
        rcnt[tid] = (pstart[c1] + pcnt[c1]) - s;   // x-contiguous range
    }
    __syncthreads();
    if (tid == 0) {
        unsigned int acc = 0; ro[0] = 0;
        for (int t = 0; t < nrow; ++t) { acc += rcnt[t]; ro[t+1] = acc; }
    }
    __syncthreads();
    const unsigned int total = ro[nrow];
    const bool ovf = (total > CAND_MAX);
    if (!ovf) {
        for (unsigned int i = tid; i < total; i += 256) {
            int lo = 0, hi = nrow;
            while (hi - lo > 1) { int mid = (lo + hi) >> 1; if (ro[mid] <= i) lo = mid; else hi = mid; }
            const unsigned int src = rs[lo] + (i - ro[lo]);
            cand[i] = pg[src];
            cidx[i] = pid[src];
        }
    }
    __syncthreads();

    const float w = 1.0f / (float)GD;
    const float thresh = 4.f * w * w * 0.999f;
    const int grp = tid >> 4, l16 = tid & 15;
    const unsigned int qs = qstart[n*GC + c];

#define INS4(d, i) { \
        bool L3 = ((d) < bd3) || ((d) == bd3 && (i) < bi3); \
        bool L2 = ((d) < bd2) || ((d) == bd2 && (i) < bi2); \
        bool L1 = ((d) < bd1) || ((d) == bd1 && (i) < bi1); \
        bool L0 = ((d) < bd0) || ((d) == bd0 && (i) < bi0); \
        bd3 = L3 ? (L2 ? bd2 : (d)) : bd3;  bi3 = L3 ? (L2 ? bi2 : (i)) : bi3; \
        bd2 = L2 ? (L1 ? bd1 : (d)) : bd2;  bi2 = L2 ? (L1 ? bi1 : (i)) : bi2; \
        bd1 = L1 ? (L0 ? bd0 : (d)) : bd1;  bi1 = L1 ? (L0 ? bi0 : (i)) : bi1; \
        bd0 = L0 ? (d) : bd0;               bi0 = L0 ? (i) : bi0; }

#define MERGE16() { \
        float bd[4] = { bd0, bd1, bd2, bd3 }; \
        int   bi[4] = { bi0, bi1, bi2, bi3 }; \
        for (int mask = 1; mask < 16; mask <<= 1) { \
            float od[4]; int oi[4]; \
            for (int j = 0; j < 4; ++j) { od[j] = __shfl_xor(bd[j], mask); \
                                          oi[j] = __shfl_xor(bi[j], mask); } \
            float e[4]; int ei[4]; \
            for (int j = 0; j < 4; ++j) { \
                float ad = bd[j], xd = od[3-j]; \
                int   ai = bi[j], xi = oi[3-j]; \
                bool ta = (ad < xd) || (ad == xd && ai < xi); \
                e[j] = ta ? ad : xd; ei[j] = ta ? ai : xi; \
            } \
            { bool sw = (e[2] < e[0]) || (e[2] == e[0] && ei[2] < ei[0]); \
              if (sw) { float td=e[0]; e[0]=e[2]; e[2]=td; int ti=ei[0]; ei[0]=ei[2]; ei[2]=ti; } } \
            { bool sw = (e[3] < e[1]) || (e[3] == e[1] && ei[3] < ei[1]); \
              if (sw) { float td=e[1]; e[1]=e[3]; e[3]=td; int ti=ei[1]; ei[1]=ei[3]; ei[3]=ti; } } \
            { bool sw = (e[1] < e[0]) || (e[1] == e[0] && ei[1] < ei[0]); \
              if (sw) { float td=e[0]; e[0]=e[1]; e[1]=td; int ti=ei[0]; ei[0]=ei[1]; ei[1]=ti; } } \
            { bool sw = (e[3] < e[2]) || (e[3] == e[2] && ei[3] < ei[2]); \
              if (sw) { float td=e[2]; e[2]=e[3]; e[3]=td; int ti=ei[2]; ei[2]=ei[3]; ei[3]=ti; } } \
            for (int j = 0; j < 4; ++j) { bd[j] = e[j]; bi[j] = ei[j]; } \
        } \
        bd0 = bd[0]; bd1 = bd[1]; bd2 = bd[2]; bd3 = bd[3]; \
        bi0 = bi[0]; bi1 = bi[1]; bi2 = bi[2]; bi3 = bi[3]; }

#pragma unroll 1
    for (unsigned int qb = 0; qb < qn; qb += 16) {
        const unsigned int qi = qb + grp;
        if (qi >= qn) continue;
        const int q = qid[qs + qi];
        const float cx = coords[3*q], cy = coords[3*q+1], cz = coords[3*q+2];
        const float ccq = fmaf(cx, cx, fmaf(cy, cy, cz*cz));

        float bd0 = FLT_MAX, bd1 = FLT_MAX, bd2 = FLT_MAX, bd3 = FLT_MAX;
        int   bi0 = 0x7fffffff, bi1 = 0x7fffffff, bi2 = 0x7fffffff, bi3 = 0x7fffffff;

        if (!ovf) {
#pragma unroll 1
            for (unsigned int j = l16; j < total; j += 16) {
                const float4 P = cand[j];
                const int i = cidx[j];
                const float dt = fmaf(cx, P.x, fmaf(cy, P.y, cz * P.z));
                const float d = fmaf(-2.0f, dt, ccq + P.w);
                INS4(d, i)
            }
            MERGE16()
        }
        if (ovf || !(bd3 < thresh)) {
            bd0 = bd1 = bd2 = bd3 = FLT_MAX;
            bi0 = bi1 = bi2 = bi3 = 0x7fffffff;
#pragma unroll 1
            for (int j = l16; j < PP; j += 16) {
                const float4 P = pg[n*PP + j];
                const int i = pid[n*PP + j];
                const float dt = fmaf(cx, P.x, fmaf(cy, P.y, cz * P.z));
                const float d = fmaf(-2.0f, dt, ccq + P.w);
                INS4(d, i)
            }
            MERGE16()
        }
        if (l16 == 0) {
            *(float4*)(odist + (size_t)q*4) = make_float4(bd0, bd1, bd2, bd3);
            *(int4*)(oidx + (size_t)q*4)    = make_int4(bi0, bi1, bi2, bi3);
        }
    }
#undef INS4
#undef MERGE16
}

// ------------------------------------------------------------------
__global__ __launch_bounds__(1024) void k_sums(const float* __restrict__ dist,
                                               float* __restrict__ sums) {
    const int b = blockIdx.x;            // n*4+k, 8 blocks
    const int n = b >> 2, k = b & 3;
    float s = 0.f;
    for (int m = threadIdx.x; m < MQ; m += 1024)
        s += 1.0f / dist[((size_t)n * MQ + m) * 4 + k];
    __shared__ float red[1024];
    red[threadIdx.x] = s;
    __syncthreads();
    for (int off = 512; off > 0; off >>= 1) {
        if (threadIdx.x < off) red[threadIdx.x] += red[threadIdx.x + off];
        __syncthreads();
    }
    if (threadIdx.x == 0) sums[b] = red[0];
}

// ------------------------------------------------------------------
static __device__ __forceinline__ float harm_val(int h, float rx, float ry, float rz) {
    if (h >= 27) return 0.f;
    float v;
    if (h < 24) {
        int base = (h < 12) ? h : (h - 12);
        float rv = (base >> 2) == 0 ? rx : ((base >> 2) == 1 ? ry : rz);
        float e = rv * (float)(1 << (base & 3));
        v = (h < 12) ? sinf(e) : cosf(e);
    } else {
        v = (h == 24) ? rx : ((h == 25) ? ry : rz);
    }
    return v;
}

// gemv: activations per-lane from S, weights broadcast uint4 from LDS W.
// acc is created and consumed INSIDE one phase (no cross-stage liveness).
template<int DIN2, int DOUT, int TILE>
__device__ __forceinline__ void gemv_l(const unsigned int* Xp, int lane,
                                       const unsigned int* Wl,
                                       const float* __restrict__ bias,
                                       int j0, float (&acc)[TILE]) {
    static_assert(TILE % 4 == 0, "");
#pragma unroll
    for (int u = 0; u < TILE; ++u) acc[u] = bias[j0 + u];
#pragma unroll
    for (int i2 = 0; i2 < DIN2; ++i2) {
        const unsigned int xv = Xp[i2 * 64 + lane];
        const uint4* wr = (const uint4*)(Wl + i2 * DOUT + j0);
#pragma unroll
        for (int t = 0; t < TILE/4; ++t) {
            const uint4 w4 = wr[t];
            acc[4*t+0] = dot2(xv, w4.x, acc[4*t+0]);
            acc[4*t+1] = dot2(xv, w4.y, acc[4*t+1]);
            acc[4*t+2] = dot2(xv, w4.z, acc[4*t+2]);
            acc[4*t+3] = dot2(xv, w4.w, acc[4*t+3]);
        }
    }
}

// ------------------------------------------------------------------
// main v13: stage-then-compute. S 32 KB activations + W 32 KB weights = 64 KB,
// 2 blocks/CU. Every phase's weights staged whole (no K-split, no acc across
// barriers -> no spill). Weights read via broadcast ds_read_b128.
//
// S rows (u32 x [64]): neighbor passes: p2out 0..63 (k*16+wv), x59 64..93,
// h1 96..127. Dense: feat 64..95; fw1out 0..63; fw2out 64..127; fw3out 0..63;
// ray-harm 64..77; rw1out 78..109.
__global__ __launch_bounds__(1024, 2) void k_main(
    const float* __restrict__ coords, const float* __restrict__ dirs,
    const float* __restrict__ pts, const float* __restrict__ tex_raw,
    const float* __restrict__ tex_t, const float* __restrict__ emb,
    const unsigned int* __restrict__ wp,
    const float* __restrict__ pb1, const float* __restrict__ pb2,
    const float* __restrict__ fb1, const float* __restrict__ fb2,
    const float* __restrict__ fb3, const float* __restrict__ db,
    const float* __restrict__ rb1, const float* __restrict__ rb2,
    const int* __restrict__ idxbuf, const float* __restrict__ distbuf,
    const float* __restrict__ sums, float* __restrict__ out, int use_tex_t)
{
    __shared__ unsigned int S[128 * 64];              // 32 KB
    __shared__ __align__(16) unsigned int W[8192];    // 32 KB
    const int tid  = threadIdx.x;
    const int lane = tid & 63;
    const int wv   = __builtin_amdgcn_readfirstlane(tid >> 6);   // 0..15
    const int q0   = blockIdx.x * 64;
    const int n    = q0 >> 14;
    const int q    = q0 + lane;

    // vectorized stage: wp offsets/lens are all 16B-aligned multiples of 4
#define STAGE(dstu4, srcoff, len) { \
        const uint4* s4_ = (const uint4*)(wp + (srcoff)); \
        for (int i_ = tid; i_ < (len)/4; i_ += 1024) ((uint4*)W)[(dstu4) + i_] = s4_[i_]; }

    // ---------- tex sampling -> fp32 regs (2 ch/wave) ----------
    float tex_acc[2] = {0.f, 0.f};
    {
        const int g = wv;
        const float cx = coords[q*3+0], cy = coords[q*3+1], cz = coords[q*3+2];
#pragma unroll
        for (int pl = 0; pl < 3; ++pl) {
            float gx = (pl == 2) ? cz : cx;
            float gy = (pl == 0) ? cy : ((pl == 1) ? cz : cx);
            float x = (gx + 1.f) * 128.f - 0.5f;
            float y = (gy + 1.f) * 128.f - 0.5f;
            float x0f = floorf(x), y0f = floorf(y);
            float wx1 = x - x0f, wy1 = y - y0f;
            float wx0 = 1.f - wx1, wy0 = 1.f - wy1;
            int x0 = (int)x0f, y0 = (int)y0f;
            int n3 = n * 3 + pl;
            int  xs[4] = { x0, x0+1, x0,   x0+1 };
            int  ys[4] = { y0, y0,   y0+1, y0+1 };
            float wt[4] = { wx0*wy0, wx1*wy0, wx0*wy1, wx1*wy1 };
#pragma unroll
            for (int c = 0; c < 4; ++c) {
                int xi = xs[c], yi = ys[c];
                if (xi >= 0 && xi < HPX && yi >= 0 && yi < HPX) {
                    float wgt = wt[c];
                    if (use_tex_t) {
                        const float2 a = *(const float2*)(tex_t +
                            (((size_t)n3 * HWSZ + (size_t)yi * HPX + xi) * 32 + g * 2));
                        tex_acc[0] = fmaf(wgt, a.x, tex_acc[0]);
                        tex_acc[1] = fmaf(wgt, a.y, tex_acc[1]);
                    } else {
                        size_t base = ((size_t)(n3 * 32 + g * 2)) * HWSZ + (size_t)yi * HPX + xi;
                        tex_acc[0] = fmaf(wgt, tex_raw[base], tex_acc[0]);
                        tex_acc[1] = fmaf(wgt, tex_raw[base + HWSZ], tex_acc[1]);
                    }
                }
            }
        }
        tex_acc[0] *= (1.f / 3.f); tex_acc[1] *= (1.f / 3.f);
    }

    // stage pw1 @0 (1920 u32) + pw2 @2048 (1024 u32); resident all 4 passes
    STAGE(0, WP_PW1, 1920)
    STAGE(512, WP_PW2, 1024)
    __syncthreads();

    // ---------- neighbor loop: 4 single-neighbor passes ----------
#pragma unroll 1
    for (int k = 0; k < KNN; ++k) {
        // A_k: x59 -> rows 64..93 (emb 64..79, harm 80..93)
        {
            const int id = idxbuf[(size_t)q*4 + k];
            if (wv < 8) {
                const float4 e = *(const float4*)(emb + (size_t)id * 32 + wv*4);
                S[(64 + 2*wv    )*64 + lane] = pk2(e.x, e.y);
                S[(64 + 2*wv + 1)*64 + lane] = pk2(e.z, e.w);
            } else {
                const int w8 = wv - 8;
                const float cx = coords[q*3+0], cy = coords[q*3+1], cz = coords[q*3+2];
                const float nx = pts[((size_t)n*PP + id)*3 + 0];
                const float ny = pts[((size_t)n*PP + id)*3 + 1];
                const float nz = pts[((size_t)n*PP + id)*3 + 2];
                float rx = cx - nx, ry = cy - ny, rz = cz - nz;
                float nrm = sqrtf(fmaf(rx, rx, fmaf(ry, ry, rz*rz)));
                float inv = 1.f / fmaxf(nrm, 1e-12f);
                rx *= inv; ry *= inv; rz *= inv;
                if (w8 < 7) {
#pragma unroll
                    for (int t = 0; t < 2; ++t) {
                        const int pr = 2*w8 + t;          // 0..13
                        S[(80 + pr)*64 + lane] =
                            pk2(harm_val(2*pr, rx, ry, rz), harm_val(2*pr + 1, rx, ry, rz));
                    }
                }
            }
        }
        __syncthreads();
        // B_k: p1 59->64 relu (W@0) -> h1 rows 96..127
        {
            float acc[4];
            gemv_l<30, 64, 4>(S + 64*64, lane, W, pb1, wv * 4, acc);
            S[(96 + 2*wv    )*64 + lane] = pk2(fmaxf(acc[0], 0.f), fmaxf(acc[1], 0.f));
            S[(96 + 2*wv + 1)*64 + lane] = pk2(fmaxf(acc[2], 0.f), fmaxf(acc[3], 0.f));
        }
        __syncthreads();
        // C_k: p2 64->32 (W@2048), wk-scaled -> row k*16 + wv
        {
            float acc[2];
            acc[0] = pb2[wv*2 + 0]; acc[1] = pb2[wv*2 + 1];
#pragma unroll
            for (int i2 = 0; i2 < 32; ++i2) {
                const unsigned int xv = S[(96 + i2)*64 + lane];
                acc[0] = dot2(xv, W[2048 + i2*32 + wv*2 + 0], acc[0]);
                acc[1] = dot2(xv, W[2048 + i2*32 + wv*2 + 1], acc[1]);
            }
            const float dist = distbuf[(size_t)q*4 + k];
            const float wk = (1.0f / dist) / sums[n*4 + k];
            S[(k*16 + wv)*64 + lane] = pk2(wk * acc[0], wk * acc[1]);
        }
        __syncthreads();
    }

    // ---------- feat -> rows 64..95; stage fw1 ----------
    {
        S[(64 + wv)*64 + lane] = pk2(tex_acc[0], tex_acc[1]);
        float a = 0.f, b = 0.f;
#pragma unroll
        for (int k = 0; k < 4; ++k) {
            float2 v = upk(S[(k*16 + wv)*64 + lane]);
            a += v.x; b += v.y;
        }
        S[(80 + wv)*64 + lane] = pk2(a, b);
    }
    STAGE(0, WP_FW1, 4096)
    __syncthreads();
    // ---------- E: fw1 64->128 relu, rows 64..95 -> rows 0..63 ----------
    {
        float acc[8];
        gemv_l<32, 128, 8>(S + 64*64, lane, W, fb1, wv * 8, acc);
#pragma unroll
        for (int u = 0; u < 4; ++u)
            S[(4*wv + u)*64 + lane] = pk2(fmaxf(acc[2*u], 0.f), fmaxf(acc[2*u+1], 0.f));
    }
    __syncthreads();
    STAGE(0, WP_FW2, 8192)
    __syncthreads();
    // ---------- F: fw2 128->128 relu, rows 0..63 -> rows 64..127 ----------
    {
        float acc[8];
        gemv_l<64, 128, 8>(S, lane, W, fb2, wv * 8, acc);
#pragma unroll
        for (int u = 0; u < 4; ++u)
            S[(64 + 4*wv + u)*64 + lane] = pk2(fmaxf(acc[2*u], 0.f), fmaxf(acc[2*u+1], 0.f));
    }
    __syncthreads();
    STAGE(0, WP_FW3, 8192)
    __syncthreads();
    // ---------- G: fw3 128->128, rows 64..127 -> rows 0..63 ----------
    {
        float acc[8];
        gemv_l<64, 128, 8>(S + 64*64, lane, W, fb3, wv * 8, acc);
#pragma unroll
        for (int u = 0; u < 4; ++u)
            S[(4*wv + u)*64 + lane] = pk2(acc[2*u], acc[2*u+1]);
    }
    __syncthreads();
    // ---------- stage rw1@0, rw2@1248(u4), dw@1504(u4); ray-harm rows 64..77 ----------
    STAGE(0, WP_RW1, 4992)       // rw1: [78][64] u32 0..4991
    STAGE(1248, WP_RW2, 1024)    // rw2 at u32 4992..6015
    STAGE(1504, WP_DW, 64)       // dw  at u32 6016..6079
    if (wv < 14) {
        float dx = dirs[q*3+0], dy = dirs[q*3+1], dz = dirs[q*3+2];
        float dn = sqrtf(fmaf(dx, dx, fmaf(dy, dy, dz*dz)));
        float inv = 1.f / fmaxf(dn, 1e-12f);
        dx *= inv; dy *= inv; dz *= inv;
        S[(64 + wv)*64 + lane] = pk2(harm_val(2*wv, dx, dy, dz),
                                     harm_val(2*wv + 1, dx, dy, dz));
    }
    __syncthreads();
    // ---------- I: rw1 155->64 relu; rows 0..63 + 64..77 -> rows 78..109 ----------
    {
        const int j0 = wv * 4;
        float acc[4];
        gemv_l<78, 64, 4>(S, lane, W, rb1, j0, acc);   // i2 0..77 contiguous rows!
        S[(78 + 2*wv    )*64 + lane] = pk2(fmaxf(acc[0], 0.f), fmaxf(acc[1], 0.f));
        S[(78 + 2*wv + 1)*64 + lane] = pk2(fmaxf(acc[2], 0.f), fmaxf(acc[3], 0.f));
    }
    __syncthreads();
    // ---------- J: rw2 64->32 + sigmoid; density (wave 15) ----------
    {
        float acc[2];
        acc[0] = rb2[wv*2 + 0]; acc[1] = rb2[wv*2 + 1];
#pragma unroll
        for (int i2 = 0; i2 < 32; ++i2) {
            const unsigned int xv = S[(78 + i2)*64 + lane];
            acc[0] = dot2(xv, W[4992 + i2*32 + wv*2 + 0], acc[0]);
            acc[1] = dot2(xv, W[4992 + i2*32 + wv*2 + 1], acc[1]);
        }
#pragma unroll
        for (int u = 0; u < 2; ++u) {
            int j = wv*2 + u;
            float v = acc[u];
            if (j < 3) v = 1.002f * (1.f / (1.f + expf(-v))) - 0.001f;
            out[OUT_RGB_OFF + (size_t)q*32 + j] = v;
        }
        if (wv == 15) {
            float z = db[0];
#pragma unroll 1
            for (int i2 = 0; i2 < 64; ++i2)
                z = dot2(S[i2*64 + lane], W[6016 + i2], z);
            const float cx = coords[q*3+0], cy = coords[q*3+1], cz = coords[q*3+2];
            float selv = (cx > -1.f && cx < 1.f && cy > -1.f && cy < 1.f &&
                          cz > -1.f && cz < 1.f) ? 1.f : 0.f;
            float t10 = 10.f * z;
            float sp = (t10 > 20.f) ? t10 : log1pf(expf(t10));
            float raw = sp * 0.1f * selv;
            out[q] = 1.f - expf(-raw);
        }
    }
#undef STAGE
}

// ------------------------------------------------------------------
extern "C" void kernel_launch(void* const* d_in, const int* in_sizes, int n_in,
                              void* d_out, int out_size, void* d_ws, size_t ws_size,
                              hipStream_t stream) {
    (void)in_sizes; (void)n_in; (void)out_size;
    const float* coords = (const float*)d_in[0];
    const float* dirs   = (const float*)d_in[1];
    const float* pts    = (const float*)d_in[2];
    const float* tex    = (const float*)d_in[3];
    const float* emb    = (const float*)d_in[4];
    const float* pw1 = (const float*)d_in[5];  const float* pb1 = (const float*)d_in[6];
    const float* pw2 = (const float*)d_in[7];  const float* pb2 = (const float*)d_in[8];
    const float* fw1 = (const float*)d_in[9];  const float* fb1 = (const float*)d_in[10];
    const float* fw2 = (const float*)d_in[11]; const float* fb2 = (const float*)d_in[12];
    const float* fw3 = (const float*)d_in[13]; const float* fb3 = (const float*)d_in[14];
    const float* dw  = (const float*)d_in[15]; const float* db  = (const float*)d_in[16];
    const float* rw1 = (const float*)d_in[17]; const float* rb1 = (const float*)d_in[18];
    const float* rw2 = (const float*)d_in[19]; const float* rb2 = (const float*)d_in[20];

    float*        out     = (float*)d_out;
    int*          wsidx   = (int*)d_ws;
    float*        wssums  = (float*)((char*)d_ws + WS_SUMS_OFF);
    unsigned int* wspcnt  = (unsigned int*)((char*)d_ws + WS_PCNT_OFF);
    unsigned int* wspsta  = (unsigned int*)((char*)d_ws + WS_PSTART_OFF);
    unsigned int* wspcur  = (unsigned int*)((char*)d_ws + WS_PCUR_OFF);
    unsigned int* wsqcnt  = (unsigned int*)((char*)d_ws + WS_QCNT_OFF);
    unsigned int* wsqsta  = (unsigned int*)((char*)d_ws + WS_QSTART_OFF);
    unsigned int* wsqcur  = (unsigned int*)((char*)d_ws + WS_QCUR_OFF);
    int*          wsqid   = (int*)((char*)d_ws + WS_QID_OFF);
    float4*       wspg    = (float4*)((char*)d_ws + WS_PG_OFF);
    int*          wspid   = (int*)((char*)d_ws + WS_PID_OFF);
    unsigned int* wswp    = (unsigned int*)((char*)d_ws + WS_WP_OFF);
    float*        wstex   = (float*)((char*)d_ws + WS_TEX_OFF);

    const size_t need_tex = WS_TEX_OFF + (size_t)6 * HWSZ * 32 * 4;
    const int use_t = (ws_size >= need_tex) ? 1 : 0;

    PackArgs pa;
    pa.src[0] = pw1; pa.off[0] = WP_PW1; pa.din[0] = 59;  pa.dout[0] = 64;
    pa.src[1] = pw2; pa.off[1] = WP_PW2; pa.din[1] = 64;  pa.dout[1] = 32;
    pa.src[2] = fw1; pa.off[2] = WP_FW1; pa.din[2] = 64;  pa.dout[2] = 128;
    pa.src[3] = fw2; pa.off[3] = WP_FW2; pa.din[3] = 128; pa.dout[3] = 128;
    pa.src[4] = fw3; pa.off[4] = WP_FW3; pa.din[4] = 128; pa.dout[4] = 128;
    pa.src[5] = dw;  pa.off[5] = WP_DW;  pa.din[5] = 128; pa.dout[5] = 1;
    pa.src[6] = rw1; pa.off[6] = WP_RW1; pa.din[6] = 155; pa.dout[6] = 64;
    pa.src[7] = rw2; pa.off[7] = WP_RW2; pa.din[7] = 64;  pa.dout[7] = 32;

    const int nitems = NB*PP + NQ;
    hipMemsetAsync((char*)d_ws + WS_PCNT_OFF, 0, WS_QSTART_OFF - WS_PCNT_OFF, stream);
    k_pack<<<dim3(32, 8), 256, 0, stream>>>(pa, wswp);
    if (use_t) k_transpose<<<6 * 256, 256, 0, stream>>>(tex, wstex);
    k_count<<<(nitems + 255)/256, 256, 0, stream>>>(pts, coords, wspcnt, wsqcnt);
    k_scan2<<<1, 1024, 0, stream>>>(wspcnt, wspsta, wspcur, wsqcnt, wsqsta, wsqcur);
    k_scatter<<<(nitems + 255)/256, 256, 0, stream>>>(pts, coords, wspcur, wsqcur,
                                                      wspg, wspid, wsqid);
    k_knn_cell<<<NB*GC, 256, 0, stream>>>(coords, wspsta, wspcnt, wspg, wspid,
                                          wsqsta, wsqcnt, wsqid,
                                          out + OUT_DIST_OFF, wsidx);
    k_sums<<<8, 1024, 0, stream>>>(out + OUT_DIST_OFF, wssums);
    k_main<<<NQ / 64, 1024, 0, stream>>>(coords, dirs, pts, tex, wstex, emb,
                                         wswp, pb1, pb2, fb1, fb2, fb3, db, rb1, rb2,
                                         wsidx, out + OUT_DIST_OFF, wssums, out, use_t);
}

// Round 14
// 280.420 us; speedup vs baseline: 2.2036x; 1.0740x over previous
//
#include <hip/hip_runtime.h>
#include <float.h>
#include <math.h>

#define NB 2
#define MQ 16384
#define NQ (NB*MQ)          // 32768 queries
#define PP 5023
#define KNN 4
#define HPX 256
#define HWSZ (HPX*HPX)      // 65536
#define GD 12               // grid dim
#define GC (GD*GD*GD)       // 1728 cells
#define CAND_MAX 1024

// output layout (floats): densities[NQ], rgb[NQ*32], dist[NQ*4]
#define OUT_RGB_OFF  ((size_t)NQ)
#define OUT_DIST_OFF ((size_t)NQ + (size_t)NQ*32)

// workspace layout (bytes)
#define WS_SUMS_OFF   ((size_t)0x80000)
#define WS_PCNT_OFF   ((size_t)0x81000)
#define WS_PSTART_OFF ((size_t)0x85000)
#define WS_PCUR_OFF   ((size_t)0x89000)
#define WS_QCNT_OFF   ((size_t)0x8D000)
#define WS_QSTART_OFF ((size_t)0x91000)
#define WS_QCUR_OFF   ((size_t)0x95000)
#define WS_QID_OFF    ((size_t)0x99000)      // 32768*4 = 128 KB
#define WS_PG_OFF     ((size_t)0xC0000)      // 2*5023*16
#define WS_PID_OFF    ((size_t)0xF0000)      // 2*5023*4
#define WS_WP_OFF     ((size_t)0x100000)     // 29504 u32
#define WS_TEX_OFF    ((size_t)0x120000)     // 25.2 MB packed-f16 tex

// packed-weight sub-offsets (u32 units)
#define WP_PW1 0
#define WP_PW2 1920
#define WP_FW1 2944
#define WP_FW2 7040
#define WP_FW3 15232
#define WP_DW  23424
#define WP_RW1 23488
#define WP_RW2 28480

typedef __attribute__((ext_vector_type(2))) _Float16 half2v;

static __device__ __forceinline__ unsigned int pk2(float a, float b) {
    half2v h; h[0] = (_Float16)a; h[1] = (_Float16)b;   // RNE converts
    return __builtin_bit_cast(unsigned int, h);
}
static __device__ __forceinline__ float2 upk(unsigned int u) {
    half2v h = __builtin_bit_cast(half2v, u);
    return make_float2((float)h[0], (float)h[1]);
}
static __device__ __forceinline__ float dot2(unsigned int a, unsigned int b, float c) {
    return __builtin_amdgcn_fdot2(__builtin_bit_cast(half2v, a),
                                  __builtin_bit_cast(half2v, b), c, false);
}
static __device__ __forceinline__ int cell_of(float x) {
    int g = (int)(x * (float)GD);
    return (g < 0) ? 0 : ((g > GD-1) ? GD-1 : g);
}

// ------------------------------------------------------------------
struct PackArgs {
    const float* src[8];
    int off[8]; int din[8]; int dout[8];
};
__global__ __launch_bounds__(256) void k_pack(PackArgs a, unsigned int* wp) {
    const int mid = blockIdx.y;
    const int idx = blockIdx.x * 256 + threadIdx.x;
    const int DIN = a.din[mid], DOUT = a.dout[mid];
    const int din2 = (DIN + 1) >> 1;
    if (idx >= din2 * DOUT) return;
    const int i2 = idx / DOUT, j = idx - i2 * DOUT;
    const float* s = a.src[mid];
    const float lo = s[(2*i2) * DOUT + j];
    const float hi = (2*i2 + 1 < DIN) ? s[(2*i2 + 1) * DOUT + j] : 0.f;
    wp[a.off[mid] + idx] = pk2(lo, hi);
}

// ------------------------------------------------------------------
// texture transpose + f16 pack: [n3][32][HW] fp32 -> [n3][HW][16] u32
__global__ __launch_bounds__(256) void k_transpose(const float* __restrict__ src,
                                                   unsigned int* __restrict__ dst) {
    const int tid = threadIdx.x;
    const int b = blockIdx.x;            // 6*256 blocks
    const int n3 = b >> 8;
    const int hw = ((b & 255) << 8) + tid;
    const float* s = src + (size_t)n3 * 32 * HWSZ + hw;
    float v[32];
#pragma unroll
    for (int c = 0; c < 32; ++c) v[c] = s[(size_t)c * HWSZ];
    uint4* d = (uint4*)(dst + ((size_t)n3 * HWSZ + hw) * 16);
#pragma unroll
    for (int c = 0; c < 4; ++c)
        d[c] = make_uint4(pk2(v[8*c], v[8*c+1]), pk2(v[8*c+2], v[8*c+3]),
                          pk2(v[8*c+4], v[8*c+5]), pk2(v[8*c+6], v[8*c+7]));
}

// ------------------------------------------------------------------
// fused bucket build: points then queries
__global__ __launch_bounds__(256) void k_count(const float* __restrict__ pts,
                                               const float* __restrict__ coords,
                                               unsigned int* __restrict__ pcnt,
                                               unsigned int* __restrict__ qcnt) {
    const int i = blockIdx.x * 256 + threadIdx.x;
    if (i < NB * PP) {
        const int n = (i >= PP) ? 1 : 0;
        const float px = pts[3*i], py = pts[3*i+1], pz = pts[3*i+2];
        const int c = (cell_of(pz)*GD + cell_of(py))*GD + cell_of(px);
        atomicAdd(&pcnt[n*GC + c], 1u);
    } else if (i - NB*PP < NQ) {
        const int q = i - NB*PP;
        const int n = q >> 14;
        const float cx = coords[3*q], cy = coords[3*q+1], cz = coords[3*q+2];
        const int c = (cell_of(cz)*GD + cell_of(cy))*GD + cell_of(cx);
        atomicAdd(&qcnt[n*GC + c], 1u);
    }
}

__global__ __launch_bounds__(1024) void k_scan2(const unsigned int* __restrict__ pcnt,
                                                unsigned int* __restrict__ psta,
                                                unsigned int* __restrict__ pcur,
                                                const unsigned int* __restrict__ qcnt,
                                                unsigned int* __restrict__ qsta,
                                                unsigned int* __restrict__ qcur) {
    __shared__ unsigned int sc[1024];
    const int t = threadIdx.x;
#pragma unroll 1
    for (int which = 0; which < 2; ++which) {
        const unsigned int* cnt = which ? qcnt : pcnt;
        unsigned int* start  = which ? qsta : psta;
        unsigned int* cursor = which ? qcur : pcur;
        const int stride = which ? MQ : PP;
#pragma unroll 1
        for (int n = 0; n < 2; ++n) {
            const unsigned int* c = cnt + n*GC;
            unsigned int a = (2*t   < GC) ? c[2*t]   : 0u;
            unsigned int b = (2*t+1 < GC) ? c[2*t+1] : 0u;
            unsigned int s = a + b;
            sc[t] = s;
            __syncthreads();
            for (int off = 1; off < 1024; off <<= 1) {
                unsigned int v = (t >= off) ? sc[t - off] : 0u;
                __syncthreads();
                sc[t] += v;
                __syncthreads();
            }
            unsigned int excl = sc[t] - s;
            unsigned int base = n * stride;
            if (2*t < GC)   { start[n*GC + 2*t]   = base + excl;
                              cursor[n*GC + 2*t]  = base + excl; }
            if (2*t+1 < GC) { start[n*GC + 2*t+1] = base + excl + a;
                              cursor[n*GC + 2*t+1]= base + excl + a; }
            __syncthreads();
        }
    }
}

__global__ __launch_bounds__(256) void k_scatter(const float* __restrict__ pts,
                                                 const float* __restrict__ coords,
                                                 unsigned int* __restrict__ pcur,
                                                 unsigned int* __restrict__ qcur,
                                                 float4* __restrict__ pg,
                                                 int* __restrict__ pid,
                                                 int* __restrict__ qid) {
    const int i = blockIdx.x * 256 + threadIdx.x;
    if (i < NB * PP) {
        const int n = (i >= PP) ? 1 : 0;
        const int local = i - n * PP;
        const float px = pts[3*i], py = pts[3*i+1], pz = pts[3*i+2];
        const int c = (cell_of(pz)*GD + cell_of(py))*GD + cell_of(px);
        const unsigned int pos = atomicAdd(&pcur[n*GC + c], 1u);
        pg[pos] = make_float4(px, py, pz, fmaf(px, px, fmaf(py, py, pz*pz)));
        pid[pos] = local;
    } else if (i - NB*PP < NQ) {
        const int q = i - NB*PP;
        const int n = q >> 14;
        const float cx = coords[3*q], cy = coords[3*q+1], cz = coords[3*q+2];
        const int c = (cell_of(cz)*GD + cell_of(cy))*GD + cell_of(cx);
        const unsigned int pos = atomicAdd(&qcur[n*GC + c], 1u);
        qid[pos] = q;
    }
}

// ------------------------------------------------------------------
// KNN (proven R13): ring<=2 candidates = <=25 x-contiguous pg ranges.
__global__ __launch_bounds__(256) void k_knn_cell(
    const float* __restrict__ coords,
    const unsigned int* __restrict__ pstart, const unsigned int* __restrict__ pcnt,
    const float4* __restrict__ pg, const int* __restrict__ pid,
    const unsigned int* __restrict__ qstart, const unsigned int* __restrict__ qcnt,
    const int* __restrict__ qid,
    float* __restrict__ odist, int* __restrict__ oidx)
{
    __shared__ float4 cand[CAND_MAX];        // 16 KB
    __shared__ int    cidx[CAND_MAX];        // 4 KB
    __shared__ unsigned int rs[25], ro[26];
    const int tid = threadIdx.x;
    const int bid = blockIdx.x;              // 2*GC
    const int n = bid / GC, c = bid % GC;
    const unsigned int qn = qcnt[n*GC + c];
    if (qn == 0) return;
    const int gz = c / (GD*GD), gy = (c / GD) % GD, gx = c % GD;

    const int x0 = max(gx-2,0), x1 = min(gx+2,GD-1);
    const int y0 = max(gy-2,0), y1 = min(gy+2,GD-1), ny = y1-y0+1;
    const int z0 = max(gz-2,0), z1 = min(gz+2,GD-1), nz = z1-z0+1;
    const int nrow = ny*nz;                  // <= 25

    __shared__ unsigned int rcnt[25];
    if (tid < nrow) {
        const int yy = y0 + tid % ny;
        const int zz = z0 + tid / ny;
        const int c0 = n*GC + (zz*GD + yy)*GD + x0;
        const int c1 = n*GC + (zz*GD + yy)*GD + x1;
        const unsigned int s = pstart[c0];
        rs[tid]   = s;
        rcnt[tid] = (pstart[c1] + pcnt[c1]) - s;   // x-contiguous range
    }
    __syncthreads();
    if (tid == 0) {
        unsigned int acc = 0; ro[0] = 0;
        for (int t = 0; t < nrow; ++t) { acc += rcnt[t]; ro[t+1] = acc; }
    }
    __syncthreads();
    const unsigned int total = ro[nrow];
    const bool ovf = (total > CAND_MAX);
    if (!ovf) {
        for (unsigned int i = tid; i < total; i += 256) {
            int lo = 0, hi = nrow;
            while (hi - lo > 1) { int mid = (lo + hi) >> 1; if (ro[mid] <= i) lo = mid; else hi = mid; }
            const unsigned int src = rs[lo] + (i - ro[lo]);
            cand[i] = pg[src];
            cidx[i] = pid[src];
        }
    }
    __syncthreads();

    const float w = 1.0f / (float)GD;
    const float thresh = 4.f * w * w * 0.999f;
    const int grp = tid >> 4, l16 = tid & 15;
    const unsigned int qs = qstart[n*GC + c];

#define INS4(d, i) { \
        bool L3 = ((d) < bd3) || ((d) == bd3 && (i) < bi3); \
        bool L2 = ((d) < bd2) || ((d) == bd2 && (i) < bi2); \
        bool L1 = ((d) < bd1) || ((d) == bd1 && (i) < bi1); \
        bool L0 = ((d) < bd0) || ((d) == bd0 && (i) < bi0); \
        bd3 = L3 ? (L2 ? bd2 : (d)) : bd3;  bi3 = L3 ? (L2 ? bi2 : (i)) : bi3; \
        bd2 = L2 ? (L1 ? bd1 : (d)) : bd2;  bi2 = L2 ? (L1 ? bi1 : (i)) : bi2; \
        bd1 = L1 ? (L0 ? bd0 : (d)) : bd1;  bi1 = L1 ? (L0 ? bi0 : (i)) : bi1; \
        bd0 = L0 ? (d) : bd0;               bi0 = L0 ? (i) : bi0; }

#define MERGE16() { \
        float bd[4] = { bd0, bd1, bd2, bd3 }; \
        int   bi[4] = { bi0, bi1, bi2, bi3 }; \
        for (int mask = 1; mask < 16; mask <<= 1) { \
            float od[4]; int oi[4]; \
            for (int j = 0; j < 4; ++j) { od[j] = __shfl_xor(bd[j], mask); \
                                          oi[j] = __shfl_xor(bi[j], mask); } \
            float e[4]; int ei[4]; \
            for (int j = 0; j < 4; ++j) { \
                float ad = bd[j], xd = od[3-j]; \
                int   ai = bi[j], xi = oi[3-j]; \
                bool ta = (ad < xd) || (ad == xd && ai < xi); \
                e[j] = ta ? ad : xd; ei[j] = ta ? ai : xi; \
            } \
            { bool sw = (e[2] < e[0]) || (e[2] == e[0] && ei[2] < ei[0]); \
              if (sw) { float td=e[0]; e[0]=e[2]; e[2]=td; int ti=ei[0]; ei[0]=ei[2]; ei[2]=ti; } } \
            { bool sw = (e[3] < e[1]) || (e[3] == e[1] && ei[3] < ei[1]); \
              if (sw) { float td=e[1]; e[1]=e[3]; e[3]=td; int ti=ei[1]; ei[1]=ei[3]; ei[3]=ti; } } \
            { bool sw = (e[1] < e[0]) || (e[1] == e[0] && ei[1] < ei[0]); \
              if (sw) { float td=e[0]; e[0]=e[1]; e[1]=td; int ti=ei[0]; ei[0]=ei[1]; ei[1]=ti; } } \
            { bool sw = (e[3] < e[2]) || (e[3] == e[2] && ei[3] < ei[2]); \
              if (sw) { float td=e[2]; e[2]=e[3]; e[3]=td; int ti=ei[2]; ei[2]=ei[3]; ei[3]=ti; } } \
            for (int j = 0; j < 4; ++j) { bd[j] = e[j]; bi[j] = ei[j]; } \
        } \
        bd0 = bd[0]; bd1 = bd[1]; bd2 = bd[2]; bd3 = bd[3]; \
        bi0 = bi[0]; bi1 = bi[1]; bi2 = bi[2]; bi3 = bi[3]; }

#pragma unroll 1
    for (unsigned int qb = 0; qb < qn; qb += 16) {
        const unsigned int qi = qb + grp;
        if (qi >= qn) continue;
        const int q = qid[qs + qi];
        const float cx = coords[3*q], cy = coords[3*q+1], cz = coords[3*q+2];
        const float ccq = fmaf(cx, cx, fmaf(cy, cy, cz*cz));

        float bd0 = FLT_MAX, bd1 = FLT_MAX, bd2 = FLT_MAX, bd3 = FLT_MAX;
        int   bi0 = 0x7fffffff, bi1 = 0x7fffffff, bi2 = 0x7fffffff, bi3 = 0x7fffffff;

        if (!ovf) {
#pragma unroll 1
            for (unsigned int j = l16; j < total; j += 16) {
                const float4 P = cand[j];
                const int i = cidx[j];
                const float dt = fmaf(cx, P.x, fmaf(cy, P.y, cz * P.z));
                const float d = fmaf(-2.0f, dt, ccq + P.w);
                INS4(d, i)
            }
            MERGE16()
        }
        if (ovf || !(bd3 < thresh)) {
            bd0 = bd1 = bd2 = bd3 = FLT_MAX;
            bi0 = bi1 = bi2 = bi3 = 0x7fffffff;
#pragma unroll 1
            for (int j = l16; j < PP; j += 16) {
                const float4 P = pg[n*PP + j];
                const int i = pid[n*PP + j];
                const float dt = fmaf(cx, P.x, fmaf(cy, P.y, cz * P.z));
                const float d = fmaf(-2.0f, dt, ccq + P.w);
                INS4(d, i)
            }
            MERGE16()
        }
        if (l16 == 0) {
            *(float4*)(odist + (size_t)q*4) = make_float4(bd0, bd1, bd2, bd3);
            *(int4*)(oidx + (size_t)q*4)    = make_int4(bi0, bi1, bi2, bi3);
        }
    }
#undef INS4
#undef MERGE16
}

// ------------------------------------------------------------------
__global__ __launch_bounds__(1024) void k_sums(const float* __restrict__ dist,
                                               float* __restrict__ sums) {
    const int b = blockIdx.x;            // n*4+k, 8 blocks
    const int n = b >> 2, k = b & 3;
    float s = 0.f;
    for (int m = threadIdx.x; m < MQ; m += 1024)
        s += 1.0f / dist[((size_t)n * MQ + m) * 4 + k];
    __shared__ float red[1024];
    red[threadIdx.x] = s;
    __syncthreads();
    for (int off = 512; off > 0; off >>= 1) {
        if (threadIdx.x < off) red[threadIdx.x] += red[threadIdx.x + off];
        __syncthreads();
    }
    if (threadIdx.x == 0) sums[b] = red[0];
}

// ------------------------------------------------------------------
static __device__ __forceinline__ float harm_val(int h, float rx, float ry, float rz) {
    if (h >= 27) return 0.f;
    float v;
    if (h < 24) {
        int base = (h < 12) ? h : (h - 12);
        float rv = (base >> 2) == 0 ? rx : ((base >> 2) == 1 ? ry : rz);
        float e = rv * (float)(1 << (base & 3));
        v = (h < 12) ? sinf(e) : cosf(e);
    } else {
        v = (h == 24) ? rx : ((h == 25) ? ry : rz);
    }
    return v;
}

#define SW 128   // S row stride in u32 (128 queries per block)

// gemv, 2 queries/lane: act b64 from S (pair 2*lane), weights b128 from W.
// TILE outputs x 2 queries; acc born and dies inside one phase.
template<int DIN2, int DOUT, int TILE>
__device__ __forceinline__ void gemv2(const unsigned int* Xp, int lane,
                                      const unsigned int* Wl,
                                      const float* __restrict__ bias, int j0,
                                      float (&aa)[TILE], float (&ab)[TILE]) {
    static_assert(TILE % 4 == 0, "");
#pragma unroll
    for (int u = 0; u < TILE; ++u) { aa[u] = bias[j0 + u]; ab[u] = aa[u]; }
#pragma unroll
    for (int i2 = 0; i2 < DIN2; ++i2) {
        const uint2 xv = *(const uint2*)(Xp + i2 * SW + 2*lane);
        const uint4* wr = (const uint4*)(Wl + i2 * DOUT + j0);
#pragma unroll
        for (int t = 0; t < TILE/4; ++t) {
            const uint4 w4 = wr[t];
            aa[4*t+0] = dot2(xv.x, w4.x, aa[4*t+0]);  ab[4*t+0] = dot2(xv.y, w4.x, ab[4*t+0]);
            aa[4*t+1] = dot2(xv.x, w4.y, aa[4*t+1]);  ab[4*t+1] = dot2(xv.y, w4.y, ab[4*t+1]);
            aa[4*t+2] = dot2(xv.x, w4.z, aa[4*t+2]);  ab[4*t+2] = dot2(xv.y, w4.z, ab[4*t+2]);
            aa[4*t+3] = dot2(xv.x, w4.w, aa[4*t+3]);  ab[4*t+3] = dot2(xv.y, w4.w, ab[4*t+3]);
        }
    }
}

// ------------------------------------------------------------------
// main v14: 128 queries/block (2 per lane), S [128 rows][128 q] 64 KB +
// W 32 KB = 96 KB LDS, 1 block/CU, grid 256. Stage-then-compute weights.
__global__ __launch_bounds__(1024, 1) void k_main(
    const float* __restrict__ coords, const float* __restrict__ dirs,
    const float* __restrict__ pts, const float* __restrict__ tex_raw,
    const unsigned int* __restrict__ tex16, const float* __restrict__ emb,
    const unsigned int* __restrict__ wp,
    const float* __restrict__ pb1, const float* __restrict__ pb2,
    const float* __restrict__ fb1, const float* __restrict__ fb2,
    const float* __restrict__ fb3, const float* __restrict__ db,
    const float* __restrict__ rb1, const float* __restrict__ rb2,
    const int* __restrict__ idxbuf, const float* __restrict__ distbuf,
    const float* __restrict__ sums, float* __restrict__ out, int use_tex_t)
{
    __shared__ unsigned int S[128 * SW];              // 64 KB
    __shared__ __align__(16) unsigned int W[8192];    // 32 KB
    const int tid  = threadIdx.x;
    const int lane = tid & 63;
    const int wv   = __builtin_amdgcn_readfirstlane(tid >> 6);   // 0..15
    const int q0   = blockIdx.x * 128;                // 256 blocks
    const int n    = q0 >> 14;
    const int qa   = q0 + 2*lane, qb = qa + 1;

#define STAGE(dstu4, srcoff, len) { \
        const uint4* s4_ = (const uint4*)(wp + (srcoff)); \
        for (int i_ = tid; i_ < (len)/4; i_ += 1024) ((uint4*)W)[(dstu4) + i_] = s4_[i_]; }

    // ---------- tex sampling: wave = ch-pair g, lane = query pair ----------
    unsigned int tex_pack[2];
    {
        const int g = wv;
#pragma unroll
        for (int s = 0; s < 2; ++s) {
            const int q = qa + s;
            const float cx = coords[q*3+0], cy = coords[q*3+1], cz = coords[q*3+2];
            float a0 = 0.f, a1 = 0.f;
#pragma unroll
            for (int pl = 0; pl < 3; ++pl) {
                float gx = (pl == 2) ? cz : cx;
                float gy = (pl == 0) ? cy : ((pl == 1) ? cz : cx);
                float x = (gx + 1.f) * 128.f - 0.5f;
                float y = (gy + 1.f) * 128.f - 0.5f;
                float x0f = floorf(x), y0f = floorf(y);
                float wx1 = x - x0f, wy1 = y - y0f;
                float wx0 = 1.f - wx1, wy0 = 1.f - wy1;
                int x0 = (int)x0f, y0 = (int)y0f;
                int n3 = n * 3 + pl;
                int  xs[4] = { x0, x0+1, x0,   x0+1 };
                int  ys[4] = { y0, y0,   y0+1, y0+1 };
                float wt[4] = { wx0*wy0, wx1*wy0, wx0*wy1, wx1*wy1 };
#pragma unroll
                for (int c = 0; c < 4; ++c) {
                    int xi = xs[c], yi = ys[c];
                    if (xi >= 0 && xi < HPX && yi >= 0 && yi < HPX) {
                        float wgt = wt[c];
                        if (use_tex_t) {
                            const unsigned int v = tex16[
                                ((size_t)n3 * HWSZ + (size_t)yi * HPX + xi) * 16 + g];
                            const float2 f = upk(v);
                            a0 = fmaf(wgt, f.x, a0);
                            a1 = fmaf(wgt, f.y, a1);
                        } else {
                            size_t base = ((size_t)(n3 * 32 + g * 2)) * HWSZ + (size_t)yi * HPX + xi;
                            a0 = fmaf(wgt, tex_raw[base], a0);
                            a1 = fmaf(wgt, tex_raw[base + HWSZ], a1);
                        }
                    }
                }
            }
            tex_pack[s] = pk2(a0 * (1.f/3.f), a1 * (1.f/3.f));
        }
    }

    STAGE(0, WP_PW1, 1920)           // pw1 @ u32 0
    STAGE(512, WP_PW2, 1024)         // pw2 @ u32 2048
    __syncthreads();

    // ---------- neighbor loop: 4 single-neighbor passes ----------
#pragma unroll 1
    for (int k = 0; k < KNN; ++k) {
        // A_k: x59 -> rows 64..93 (emb 64..79, harm 80..93)
        {
#pragma unroll
            for (int s = 0; s < 2; ++s) {
                const int q = qa + s;
                const int id = idxbuf[(size_t)q*4 + k];
                if (wv < 8) {
                    const float4 e = *(const float4*)(emb + (size_t)id * 32 + wv*4);
                    S[(64 + 2*wv    )*SW + 2*lane + s] = pk2(e.x, e.y);
                    S[(64 + 2*wv + 1)*SW + 2*lane + s] = pk2(e.z, e.w);
                } else {
                    const int w8 = wv - 8;
                    if (w8 < 7) {
                        const float cx = coords[q*3+0], cy = coords[q*3+1], cz = coords[q*3+2];
                        const float nx = pts[((size_t)n*PP + id)*3 + 0];
                        const float ny = pts[((size_t)n*PP + id)*3 + 1];
                        const float nz = pts[((size_t)n*PP + id)*3 + 2];
                        float rx = cx - nx, ry = cy - ny, rz = cz - nz;
                        float nrm = sqrtf(fmaf(rx, rx, fmaf(ry, ry, rz*rz)));
                        float inv = 1.f / fmaxf(nrm, 1e-12f);
                        rx *= inv; ry *= inv; rz *= inv;
#pragma unroll
                        for (int t = 0; t < 2; ++t) {
                            const int pr = 2*w8 + t;          // 0..13
                            S[(80 + pr)*SW + 2*lane + s] =
                                pk2(harm_val(2*pr, rx, ry, rz), harm_val(2*pr + 1, rx, ry, rz));
                        }
                    }
                }
            }
        }
        __syncthreads();
        // B_k: p1 59->64 relu (W@0) -> h1 rows 96..127
        {
            float aa[4], ab[4];
            gemv2<30, 64, 4>(S + 64*SW, lane, W, pb1, wv * 4, aa, ab);
            S[(96 + 2*wv    )*SW + 2*lane + 0] = pk2(fmaxf(aa[0], 0.f), fmaxf(aa[1], 0.f));
            S[(96 + 2*wv    )*SW + 2*lane + 1] = pk2(fmaxf(ab[0], 0.f), fmaxf(ab[1], 0.f));
            S[(96 + 2*wv + 1)*SW + 2*lane + 0] = pk2(fmaxf(aa[2], 0.f), fmaxf(aa[3], 0.f));
            S[(96 + 2*wv + 1)*SW + 2*lane + 1] = pk2(fmaxf(ab[2], 0.f), fmaxf(ab[3], 0.f));
        }
        __syncthreads();
        // C_k: p2 64->32 (W@2048), wk-scaled -> row k*16 + wv
        {
            float aa[2], ab[2];
            aa[0] = pb2[wv*2 + 0]; aa[1] = pb2[wv*2 + 1];
            ab[0] = aa[0]; ab[1] = aa[1];
#pragma unroll
            for (int i2 = 0; i2 < 32; ++i2) {
                const uint2 xv = *(const uint2*)(S + (96 + i2)*SW + 2*lane);
                const unsigned int w0 = W[2048 + i2*32 + wv*2 + 0];
                const unsigned int w1 = W[2048 + i2*32 + wv*2 + 1];
                aa[0] = dot2(xv.x, w0, aa[0]);  ab[0] = dot2(xv.y, w0, ab[0]);
                aa[1] = dot2(xv.x, w1, aa[1]);  ab[1] = dot2(xv.y, w1, ab[1]);
            }
            const float da = distbuf[(size_t)qa*4 + k];
            const float dbq = distbuf[(size_t)qb*4 + k];
            const float wka = (1.0f / da)  / sums[n*4 + k];
            const float wkb = (1.0f / dbq) / sums[n*4 + k];
            S[(k*16 + wv)*SW + 2*lane + 0] = pk2(wka * aa[0], wka * aa[1]);
            S[(k*16 + wv)*SW + 2*lane + 1] = pk2(wkb * ab[0], wkb * ab[1]);
        }
        __syncthreads();
    }

    // ---------- feat -> rows 64..95 (tex 64..79, pts 80..95); stage fw1 ----------
    {
        S[(64 + wv)*SW + 2*lane + 0] = tex_pack[0];
        S[(64 + wv)*SW + 2*lane + 1] = tex_pack[1];
#pragma unroll
        for (int s = 0; s < 2; ++s) {
            float a = 0.f, b = 0.f;
#pragma unroll
            for (int k = 0; k < 4; ++k) {
                float2 v = upk(S[(k*16 + wv)*SW + 2*lane + s]);
                a += v.x; b += v.y;
            }
            S[(80 + wv)*SW + 2*lane + s] = pk2(a, b);
        }
    }
    STAGE(0, WP_FW1, 4096)
    __syncthreads();
    // ---------- E: fw1 64->128 relu, rows 64..95 -> rows 0..63 ----------
    {
        float aa[8], ab[8];
        gemv2<32, 128, 8>(S + 64*SW, lane, W, fb1, wv * 8, aa, ab);
#pragma unroll
        for (int u = 0; u < 4; ++u) {
            S[(4*wv + u)*SW + 2*lane + 0] = pk2(fmaxf(aa[2*u], 0.f), fmaxf(aa[2*u+1], 0.f));
            S[(4*wv + u)*SW + 2*lane + 1] = pk2(fmaxf(ab[2*u], 0.f), fmaxf(ab[2*u+1], 0.f));
        }
    }
    __syncthreads();
    STAGE(0, WP_FW2, 8192)
    __syncthreads();
    // ---------- F: fw2 128->128 relu, rows 0..63 -> rows 64..127 ----------
    {
        float aa[8], ab[8];
        gemv2<64, 128, 8>(S, lane, W, fb2, wv * 8, aa, ab);
#pragma unroll
        for (int u = 0; u < 4; ++u) {
            S[(64 + 4*wv + u)*SW + 2*lane + 0] = pk2(fmaxf(aa[2*u], 0.f), fmaxf(aa[2*u+1], 0.f));
            S[(64 + 4*wv + u)*SW + 2*lane + 1] = pk2(fmaxf(ab[2*u], 0.f), fmaxf(ab[2*u+1], 0.f));
        }
    }
    __syncthreads();
    STAGE(0, WP_FW3, 8192)
    __syncthreads();
    // ---------- G: fw3 128->128, rows 64..127 -> rows 0..63 ----------
    {
        float aa[8], ab[8];
        gemv2<64, 128, 8>(S + 64*SW, lane, W, fb3, wv * 8, aa, ab);
#pragma unroll
        for (int u = 0; u < 4; ++u) {
            S[(4*wv + u)*SW + 2*lane + 0] = pk2(aa[2*u], aa[2*u+1]);
            S[(4*wv + u)*SW + 2*lane + 1] = pk2(ab[2*u], ab[2*u+1]);
        }
    }
    __syncthreads();
    // ---------- stage rw1/rw2/dw; ray-harm rows 64..77 ----------
    STAGE(0, WP_RW1, 4992)       // rw1: [78][64] @ u32 0..4991
    STAGE(1248, WP_RW2, 1024)    // rw2 @ u32 4992
    STAGE(1504, WP_DW, 64)       // dw  @ u32 6016
    if (wv < 14) {
#pragma unroll
        for (int s = 0; s < 2; ++s) {
            const int q = qa + s;
            float dx = dirs[q*3+0], dy = dirs[q*3+1], dz = dirs[q*3+2];
            float dn = sqrtf(fmaf(dx, dx, fmaf(dy, dy, dz*dz)));
            float inv = 1.f / fmaxf(dn, 1e-12f);
            dx *= inv; dy *= inv; dz *= inv;
            S[(64 + wv)*SW + 2*lane + s] = pk2(harm_val(2*wv, dx, dy, dz),
                                               harm_val(2*wv + 1, dx, dy, dz));
        }
    }
    __syncthreads();
    // ---------- I: rw1 155->64 relu; rows 0..77 -> rows 78..109 ----------
    {
        float aa[4], ab[4];
        gemv2<78, 64, 4>(S, lane, W, rb1, wv * 4, aa, ab);
        S[(78 + 2*wv    )*SW + 2*lane + 0] = pk2(fmaxf(aa[0], 0.f), fmaxf(aa[1], 0.f));
        S[(78 + 2*wv    )*SW + 2*lane + 1] = pk2(fmaxf(ab[0], 0.f), fmaxf(ab[1], 0.f));
        S[(78 + 2*wv + 1)*SW + 2*lane + 0] = pk2(fmaxf(aa[2], 0.f), fmaxf(aa[3], 0.f));
        S[(78 + 2*wv + 1)*SW + 2*lane + 1] = pk2(fmaxf(ab[2], 0.f), fmaxf(ab[3], 0.f));
    }
    __syncthreads();
    // ---------- J: rw2 64->32 + sigmoid; density (wave 15) ----------
    {
        float aa[2], ab[2];
        aa[0] = rb2[wv*2 + 0]; aa[1] = rb2[wv*2 + 1];
        ab[0] = aa[0]; ab[1] = aa[1];
#pragma unroll
        for (int i2 = 0; i2 < 32; ++i2) {
            const uint2 xv = *(const uint2*)(S + (78 + i2)*SW + 2*lane);
            const unsigned int w0 = W[4992 + i2*32 + wv*2 + 0];
            const unsigned int w1 = W[4992 + i2*32 + wv*2 + 1];
            aa[0] = dot2(xv.x, w0, aa[0]);  ab[0] = dot2(xv.y, w0, ab[0]);
            aa[1] = dot2(xv.x, w1, aa[1]);  ab[1] = dot2(xv.y, w1, ab[1]);
        }
#pragma unroll
        for (int u = 0; u < 2; ++u) {
            const int j = wv*2 + u;
            float va = (u == 0) ? aa[0] : aa[1];
            float vb = (u == 0) ? ab[0] : ab[1];
            if (j < 3) {
                va = 1.002f * (1.f / (1.f + expf(-va))) - 0.001f;
                vb = 1.002f * (1.f / (1.f + expf(-vb))) - 0.001f;
            }
            out[OUT_RGB_OFF + (size_t)qa*32 + j] = va;
            out[OUT_RGB_OFF + (size_t)qb*32 + j] = vb;
        }
        if (wv == 15) {
            float za = db[0], zb = db[0];
#pragma unroll 1
            for (int i2 = 0; i2 < 64; ++i2) {
                const uint2 xv = *(const uint2*)(S + i2*SW + 2*lane);
                const unsigned int wz = W[6016 + i2];
                za = dot2(xv.x, wz, za);
                zb = dot2(xv.y, wz, zb);
            }
#pragma unroll
            for (int s = 0; s < 2; ++s) {
                const int q = qa + s;
                const float z = (s == 0) ? za : zb;
                const float cx = coords[q*3+0], cy = coords[q*3+1], cz = coords[q*3+2];
                float selv = (cx > -1.f && cx < 1.f && cy > -1.f && cy < 1.f &&
                              cz > -1.f && cz < 1.f) ? 1.f : 0.f;
                float t10 = 10.f * z;
                float sp = (t10 > 20.f) ? t10 : log1pf(expf(t10));
                float raw = sp * 0.1f * selv;
                out[q] = 1.f - expf(-raw);
            }
        }
    }
#undef STAGE
}

// ------------------------------------------------------------------
extern "C" void kernel_launch(void* const* d_in, const int* in_sizes, int n_in,
                              void* d_out, int out_size, void* d_ws, size_t ws_size,
                              hipStream_t stream) {
    (void)in_sizes; (void)n_in; (void)out_size;
    const float* coords = (const float*)d_in[0];
    const float* dirs   = (const float*)d_in[1];
    const float* pts    = (const float*)d_in[2];
    const float* tex    = (const float*)d_in[3];
    const float* emb    = (const float*)d_in[4];
    const float* pw1 = (const float*)d_in[5];  const float* pb1 = (const float*)d_in[6];
    const float* pw2 = (const float*)d_in[7];  const float* pb2 = (const float*)d_in[8];
    const float* fw1 = (const float*)d_in[9];  const float* fb1 = (const float*)d_in[10];
    const float* fw2 = (const float*)d_in[11]; const float* fb2 = (const float*)d_in[12];
    const float* fw3 = (const float*)d_in[13]; const float* fb3 = (const float*)d_in[14];
    const float* dw  = (const float*)d_in[15]; const float* db  = (const float*)d_in[16];
    const float* rw1 = (const float*)d_in[17]; const float* rb1 = (const float*)d_in[18];
    const float* rw2 = (const float*)d_in[19]; const float* rb2 = (const float*)d_in[20];

    float*        out     = (float*)d_out;
    int*          wsidx   = (int*)d_ws;
    float*        wssums  = (float*)((char*)d_ws + WS_SUMS_OFF);
    unsigned int* wspcnt  = (unsigned int*)((char*)d_ws + WS_PCNT_OFF);
    unsigned int* wspsta  = (unsigned int*)((char*)d_ws + WS_PSTART_OFF);
    unsigned int* wspcur  = (unsigned int*)((char*)d_ws + WS_PCUR_OFF);
    unsigned int* wsqcnt  = (unsigned int*)((char*)d_ws + WS_QCNT_OFF);
    unsigned int* wsqsta  = (unsigned int*)((char*)d_ws + WS_QSTART_OFF);
    unsigned int* wsqcur  = (unsigned int*)((char*)d_ws + WS_QCUR_OFF);
    int*          wsqid   = (int*)((char*)d_ws + WS_QID_OFF);
    float4*       wspg    = (float4*)((char*)d_ws + WS_PG_OFF);
    int*          wspid   = (int*)((char*)d_ws + WS_PID_OFF);
    unsigned int* wswp    = (unsigned int*)((char*)d_ws + WS_WP_OFF);
    unsigned int* wstex   = (unsigned int*)((char*)d_ws + WS_TEX_OFF);

    const size_t need_tex = WS_TEX_OFF + (size_t)6 * HWSZ * 16 * 4;
    const int use_t = (ws_size >= need_tex) ? 1 : 0;

    PackArgs pa;
    pa.src[0] = pw1; pa.off[0] = WP_PW1; pa.din[0] = 59;  pa.dout[0] = 64;
    pa.src[1] = pw2; pa.off[1] = WP_PW2; pa.din[1] = 64;  pa.dout[1] = 32;
    pa.src[2] = fw1; pa.off[2] = WP_FW1; pa.din[2] = 64;  pa.dout[2] = 128;
    pa.src[3] = fw2; pa.off[3] = WP_FW2; pa.din[3] = 128; pa.dout[3] = 128;
    pa.src[4] = fw3; pa.off[4] = WP_FW3; pa.din[4] = 128; pa.dout[4] = 128;
    pa.src[5] = dw;  pa.off[5] = WP_DW;  pa.din[5] = 128; pa.dout[5] = 1;
    pa.src[6] = rw1; pa.off[6] = WP_RW1; pa.din[6] = 155; pa.dout[6] = 64;
    pa.src[7] = rw2; pa.off[7] = WP_RW2; pa.din[7] = 64;  pa.dout[7] = 32;

    const int nitems = NB*PP + NQ;
    hipMemsetAsync((char*)d_ws + WS_PCNT_OFF, 0, WS_QSTART_OFF - WS_PCNT_OFF, stream);
    k_pack<<<dim3(32, 8), 256, 0, stream>>>(pa, wswp);
    if (use_t) k_transpose<<<6 * 256, 256, 0, stream>>>(tex, wstex);
    k_count<<<(nitems + 255)/256, 256, 0, stream>>>(pts, coords, wspcnt, wsqcnt);
    k_scan2<<<1, 1024, 0, stream>>>(wspcnt, wspsta, wspcur, wsqcnt, wsqsta, wsqcur);
    k_scatter<<<(nitems + 255)/256, 256, 0, stream>>>(pts, coords, wspcur, wsqcur,
                                                      wspg, wspid, wsqid);
    k_knn_cell<<<NB*GC, 256, 0, stream>>>(coords, wspsta, wspcnt, wspg, wspid,
                                          wsqsta, wsqcnt, wsqid,
                                          out + OUT_DIST_OFF, wsidx);
    k_sums<<<8, 1024, 0, stream>>>(out + OUT_DIST_OFF, wssums);
    k_main<<<NQ / 128, 1024, 0, stream>>>(coords, dirs, pts, tex, wstex, emb,
                                          wswp, pb1, pb2, fb1, fb2, fb3, db, rb1, rb2,
                                          wsidx, out + OUT_DIST_OFF, wssums, out, use_t);
}